// Round 2
// baseline (1427.720 us; speedup 1.0000x reference)
//
#include <hip/hip_runtime.h>

typedef unsigned short u16;
typedef unsigned int u32;
typedef __bf16 bf16_t;
typedef bf16_t bf16x8 __attribute__((ext_vector_type(8)));
typedef float f32x4 __attribute__((ext_vector_type(4)));

#define N_NODES 30000
#define N_EDGES 480000
#define BME 48  // edges per block in edge_mlp

static __device__ __forceinline__ float b2f(u16 u) {
  return __uint_as_float(((u32)u) << 16);
}
static __device__ __forceinline__ float b2f_lo(u32 w) {
  return __uint_as_float(w << 16);
}
static __device__ __forceinline__ float b2f_hi(u32 w) {
  return __uint_as_float(w & 0xffff0000u);
}
static __device__ __forceinline__ u16 f2b(float f) {
  u32 x = __float_as_uint(f);
  u32 r = (x + 0x7fffu + ((x >> 16) & 1u)) >> 16;
  return (u16)r;
}

// ---------------- dtype sniff: bf16 storage (flag=0) vs f32 storage (flag=1) ----------------
__global__ void sniff(const u16* __restrict__ h, int* __restrict__ flag) {
  if (threadIdx.x == 0) {
    int bad = 0;
    for (int i = 0; i < 1024; i++) {
      u32 e = ((u32)h[i] >> 7) & 0xFFu;
      if (e >= 0x8Eu) bad++;  // |x| >= 2^15 or Inf/NaN as bf16: impossible for N(0,1) bf16 data
    }
    *flag = (bad > 0) ? 1 : 0;
  }
}

// ---------------- convert one big array to canonical bf16 ----------------
__global__ __launch_bounds__(256) void conv_arr(const void* __restrict__ src,
                                                u16* __restrict__ dst, int n,
                                                const int* __restrict__ flag) {
  int i = blockIdx.x * 256 + threadIdx.x;
  if (i >= n) return;
  if (*flag) dst[i] = f2b(((const float*)src)[i]);
  else dst[i] = ((const u16*)src)[i];
}

struct ConvDesc { const void* s; u16* d; int n; int off; };
struct ConvTab { ConvDesc e[20]; int total; };

__global__ __launch_bounds__(256) void conv_params(ConvTab tab, const int* __restrict__ flag) {
  int i = blockIdx.x * 256 + threadIdx.x;
  if (i >= tab.total) return;
  int f = *flag;
#pragma unroll 1
  for (int a = 0; a < 20; a++) {
    int j = i - tab.e[a].off;
    if (j >= 0 && j < tab.e[a].n) {
      if (f) tab.e[a].d[j] = f2b(((const float*)tab.e[a].s)[j]);
      else tab.e[a].d[j] = ((const u16*)tab.e[a].s)[j];
      return;
    }
  }
}

// ---------------- weight transpose: dst[n*ldo + ko + k] = src[k*Nn + n] ----------------
__global__ void transpose_k(const u16* __restrict__ src, u16* __restrict__ dstp,
                            int K, int nshift, int ldo, int ko) {
  int tid = blockIdx.x * 256 + threadIdx.x;
  int Nn = 1 << nshift;
  int k = tid >> nshift, n = tid & (Nn - 1);
  if (k >= K) return;
  dstp[(size_t)n * ldo + ko + k] = src[(size_t)k * Nn + n];
}

// ---------------- build permuted+padded ep_W1^T: [256 n][544 k'] ----------------
__global__ void build_wt1(const u16* __restrict__ w1, u16* __restrict__ dstp) {
  int n = blockIdx.x;  // 0..255
  for (int kp = threadIdx.x; kp < 544; kp += 256) {
    u16 v = 0;
    int ro = -1;
    if (kp < 256) ro = kp;                       // h1[src]
    else if (kp < 512) ro = 267 + (kp - 256);    // h1[dst]
    else if (kp < 517) ro = 256 + (kp - 512);    // sm[src]
    else if (kp < 522) ro = 523 + (kp - 517);    // sm[dst]
    else if (kp < 528) ro = 261 + (kp - 522);    // efeat
    if (ro >= 0) v = w1[(size_t)ro * 256 + n];
    dstp[(size_t)n * 544 + kp] = v;
  }
}

// ---------------- generic MFMA GEMM: C = relu(concat(A0,A1) @ Bt^T + bias) ----------------
__global__ __launch_bounds__(256) void gemm_mfma(
    const u16* __restrict__ A0, const u16* __restrict__ A1, int K0, int K1,
    const u16* __restrict__ Bt, const u16* __restrict__ bias,
    u16* __restrict__ C, float* __restrict__ Cf, const int* __restrict__ flag,
    int M, int Nld) {
  __shared__ __align__(16) u16 As[128 * 40];
  __shared__ __align__(16) u16 Bs[128 * 40];
  const int t = threadIdx.x;
  const int lane = t & 63, wv = t >> 6;
  const int wm = wv & 1, wn = wv >> 1;
  const int r = lane & 15, q = lane >> 4;
  const int bm = blockIdx.x, bn = blockIdx.y;
  const int Ktot = K0 + K1;
  const bool usef = (Cf != nullptr) && (*flag != 0);

  f32x4 acc[4][4];
#pragma unroll
  for (int i = 0; i < 4; i++)
#pragma unroll
    for (int j = 0; j < 4; j++) acc[i][j] = (f32x4){0.f, 0.f, 0.f, 0.f};

  for (int kc = 0; kc < Ktot; kc += 32) {
#pragma unroll
    for (int h = 0; h < 2; h++) {
      int idx = t + h * 256;          // 0..511
      int rr = idx >> 2, qq = idx & 3;
      int rowg = bm * 128 + rr;
      uint4 av = make_uint4(0, 0, 0, 0);
      if (rowg < M) {
        const u16* p = (kc < K0) ? (A0 + (size_t)rowg * K0 + kc)
                                 : (A1 + (size_t)rowg * K1 + (kc - K0));
        av = *(const uint4*)(p + qq * 8);
      }
      *(uint4*)&As[rr * 40 + qq * 8] = av;
      int ng = bn * 128 + rr;
      uint4 bv = *(const uint4*)(Bt + (size_t)ng * Ktot + kc + qq * 8);
      *(uint4*)&Bs[rr * 40 + qq * 8] = bv;
    }
    __syncthreads();
    bf16x8 af[4], bfm[4];
#pragma unroll
    for (int mi = 0; mi < 4; mi++)
      af[mi] = *(const bf16x8*)&As[(wm * 64 + mi * 16 + r) * 40 + q * 8];
#pragma unroll
    for (int ni = 0; ni < 4; ni++)
      bfm[ni] = *(const bf16x8*)&Bs[(wn * 64 + ni * 16 + r) * 40 + q * 8];
#pragma unroll
    for (int mi = 0; mi < 4; mi++)
#pragma unroll
      for (int ni = 0; ni < 4; ni++)
        acc[mi][ni] = __builtin_amdgcn_mfma_f32_16x16x32_bf16(af[mi], bfm[ni], acc[mi][ni], 0, 0, 0);
    __syncthreads();
  }

  float bv[4];
#pragma unroll
  for (int ni = 0; ni < 4; ni++) bv[ni] = b2f(bias[bn * 128 + wn * 64 + ni * 16 + r]);
#pragma unroll
  for (int mi = 0; mi < 4; mi++) {
#pragma unroll
    for (int i = 0; i < 4; i++) {
      int rowg = bm * 128 + wm * 64 + mi * 16 + q * 4 + i;
      if (rowg >= M) continue;
#pragma unroll
      for (int ni = 0; ni < 4; ni++) {
        int colg = bn * 128 + wn * 64 + ni * 16 + r;
        float v = acc[mi][ni][i] + bv[ni];
        v = v > 0.f ? v : 0.f;
        if (usef) Cf[(size_t)rowg * Nld + colg] = v;
        else C[(size_t)rowg * Nld + colg] = f2b(v);
      }
    }
  }
}

// ---------------- scatter max: agg[dst[e]][:] = max(agg, m[src[e]][:]) ----------------
__global__ __launch_bounds__(256) void scatter_max(
    const u16* __restrict__ m, const int* __restrict__ src, const int* __restrict__ dst,
    float* __restrict__ agg, int dshift, int nE) {
  int tid = blockIdx.x * 256 + threadIdx.x;
  int e = tid >> dshift;
  if (e >= nE) return;
  int D4 = 1 << dshift;
  int j = (tid & (D4 - 1)) << 2;
  int D = D4 << 2;
  int s = src[e], d = dst[e];
  uint2 raw = *(const uint2*)(m + (size_t)s * D + j);
  float v0 = b2f_lo(raw.x), v1 = b2f_hi(raw.x), v2 = b2f_lo(raw.y), v3 = b2f_hi(raw.y);
  float* ap = agg + (size_t)d * D + j;
  float4 cur = *(const float4*)ap;
  if (v0 > cur.x) atomicMax((u32*)(ap + 0), __float_as_uint(v0));
  if (v1 > cur.y) atomicMax((u32*)(ap + 1), __float_as_uint(v1));
  if (v2 > cur.z) atomicMax((u32*)(ap + 2), __float_as_uint(v2));
  if (v3 > cur.w) atomicMax((u32*)(ap + 3), __float_as_uint(v3));
}

__global__ void f32_to_b16(const float* __restrict__ in, u16* __restrict__ out, int n) {
  int i = blockIdx.x * 256 + threadIdx.x;
  if (i < n) out[i] = f2b(in[i]);
}

// ---------------- node head: node_pred = LN(h1@W + b), sm = softmax(node_pred) ----------------
__global__ __launch_bounds__(256) void node_head(
    const u16* __restrict__ h1, const u16* __restrict__ W, const u16* __restrict__ b,
    const u16* __restrict__ g, const u16* __restrict__ beta,
    u16* __restrict__ outN, float* __restrict__ outNf, const int* __restrict__ flag,
    u16* __restrict__ smOut) {
  __shared__ float Wl[256 * 5];
  __shared__ float bl[5], gl[5], betal[5];
  int t = threadIdx.x;
#pragma unroll
  for (int c = 0; c < 5; c++) Wl[t * 5 + c] = b2f(W[t * 5 + c]);
  if (t < 5) { bl[t] = b2f(b[t]); gl[t] = b2f(g[t]); betal[t] = b2f(beta[t]); }
  __syncthreads();
  int n = blockIdx.x * 256 + t;
  if (n >= N_NODES) return;
  const bool usef = (*flag != 0);
  float acc[5] = {0.f, 0.f, 0.f, 0.f, 0.f};
  const u16* hp = h1 + (size_t)n * 256;
  for (int k8 = 0; k8 < 32; k8++) {
    uint4 v = *(const uint4*)(hp + k8 * 8);
    u32 wds[4] = {v.x, v.y, v.z, v.w};
#pragma unroll
    for (int h = 0; h < 4; h++) {
      float x0 = b2f_lo(wds[h]), x1 = b2f_hi(wds[h]);
      int k = k8 * 8 + h * 2;
#pragma unroll
      for (int c = 0; c < 5; c++)
        acc[c] += x0 * Wl[k * 5 + c] + x1 * Wl[(k + 1) * 5 + c];
    }
  }
  float x[5], mu = 0.f;
#pragma unroll
  for (int c = 0; c < 5; c++) { x[c] = acc[c] + bl[c]; mu += x[c]; }
  mu *= 0.2f;
  float var = 0.f;
#pragma unroll
  for (int c = 0; c < 5; c++) { float d = x[c] - mu; var += d * d; }
  var *= 0.2f;
  float rstd = rsqrtf(fmaxf(var, 0.f) + 1e-5f);
  float v5[5], mx = -1e30f;
#pragma unroll
  for (int c = 0; c < 5; c++) {
    v5[c] = gl[c] * (x[c] - mu) * rstd + betal[c];
    if (usef) outNf[(size_t)n * 5 + c] = v5[c];
    else outN[(size_t)n * 5 + c] = f2b(v5[c]);
    mx = fmaxf(mx, v5[c]);
  }
  float s = 0.f, ex[5];
#pragma unroll
  for (int c = 0; c < 5; c++) { ex[c] = __expf(v5[c] - mx); s += ex[c]; }
  float inv = 1.f / s;
#pragma unroll
  for (int c = 0; c < 5; c++) smOut[(size_t)n * 5 + c] = f2b(ex[c] * inv);
}

// ---------------- fused edge MLP: gather-concat -> @W1+b1 -> LN -> relu -> @W2+b2 ----------------
__global__ __launch_bounds__(256) void edge_mlp(
    const u16* __restrict__ h1, const u16* __restrict__ sm, const u16* __restrict__ ef,
    const int* __restrict__ src, const int* __restrict__ dst,
    const u16* __restrict__ wt1, const u16* __restrict__ b1,
    const u16* __restrict__ g, const u16* __restrict__ beta,
    const u16* __restrict__ w2, const u16* __restrict__ b2,
    u16* __restrict__ outE, float* __restrict__ outEf, const int* __restrict__ flag) {
  __shared__ __align__(16) u16 Ax[BME * 552];  // 48 rows x 544(+8 pad) bf16
  __shared__ int sidx[BME], didx[BME];
  __shared__ float red[4][BME][2];
  __shared__ float mr[BME][2];
  const int t = threadIdx.x;
  const int eb = blockIdx.x * BME;
  if (t < BME) { sidx[t] = src[eb + t]; didx[t] = dst[eb + t]; }
  __syncthreads();
#pragma unroll
  for (int i = 0; i < 6; i++) {
    int c = t + i * 256;  // 0..1535
    int e = c >> 5, qq = c & 31;
    uint4 v = *(const uint4*)(h1 + (size_t)sidx[e] * 256 + qq * 8);
    *(uint4*)&Ax[e * 552 + qq * 8] = v;
    uint4 w = *(const uint4*)(h1 + (size_t)didx[e] * 256 + qq * 8);
    *(uint4*)&Ax[e * 552 + 256 + qq * 8] = w;
  }
  if (t < BME * 4) {
    int e = t >> 2, j0 = (t & 3) * 8;
#pragma unroll
    for (int jj = 0; jj < 8; jj++) {
      int j = j0 + jj;
      u16 val = 0;
      if (j < 5) val = sm[(size_t)sidx[e] * 5 + j];
      else if (j < 10) val = sm[(size_t)didx[e] * 5 + (j - 5)];
      else if (j < 16) val = ef[(size_t)(eb + e) * 6 + (j - 10)];
      Ax[e * 552 + 512 + j] = val;
    }
  }
  __syncthreads();

  const int lane = t & 63, wv = t >> 6;
  const int r = lane & 15, q = lane >> 4;
  f32x4 acc[3][4];
#pragma unroll
  for (int mi = 0; mi < 3; mi++)
#pragma unroll
    for (int ni = 0; ni < 4; ni++) acc[mi][ni] = (f32x4){0.f, 0.f, 0.f, 0.f};

  int ncol[4];
#pragma unroll
  for (int ni = 0; ni < 4; ni++) ncol[ni] = wv * 64 + ni * 16 + r;
  uint4 braw[4], bnext[4];
#pragma unroll
  for (int ni = 0; ni < 4; ni++)
    braw[ni] = *(const uint4*)(wt1 + (size_t)ncol[ni] * 544 + q * 8);

  for (int kc = 0; kc < 544; kc += 32) {
    bf16x8 af[3];
#pragma unroll
    for (int mi = 0; mi < 3; mi++)
      af[mi] = *(const bf16x8*)&Ax[(mi * 16 + r) * 552 + kc + q * 8];
    if (kc + 32 < 544) {
#pragma unroll
      for (int ni = 0; ni < 4; ni++)
        bnext[ni] = *(const uint4*)(wt1 + (size_t)ncol[ni] * 544 + (kc + 32) + q * 8);
    }
#pragma unroll
    for (int mi = 0; mi < 3; mi++)
#pragma unroll
      for (int ni = 0; ni < 4; ni++)
        acc[mi][ni] = __builtin_amdgcn_mfma_f32_16x16x32_bf16(
            af[mi], __builtin_bit_cast(bf16x8, braw[ni]), acc[mi][ni], 0, 0, 0);
#pragma unroll
    for (int ni = 0; ni < 4; ni++) braw[ni] = bnext[ni];
  }

  float b1v[4], gv[4], bev[4], w20[4], w21[4];
#pragma unroll
  for (int ni = 0; ni < 4; ni++) {
    int c = ncol[ni];
    b1v[ni] = b2f(b1[c]); gv[ni] = b2f(g[c]); bev[ni] = b2f(beta[c]);
    w20[ni] = b2f(w2[c * 2]); w21[ni] = b2f(w2[c * 2 + 1]);
  }
  // pass 1: LN stats (sum, sumsq over 256 cols per edge row)
#pragma unroll
  for (int mi = 0; mi < 3; mi++)
#pragma unroll
    for (int i = 0; i < 4; i++) {
      float ps = 0.f, pq = 0.f;
#pragma unroll
      for (int ni = 0; ni < 4; ni++) {
        float x = acc[mi][ni][i] + b1v[ni];
        ps += x; pq += x * x;
      }
      for (int msk = 1; msk < 16; msk <<= 1) {
        ps += __shfl_xor(ps, msk, 64);
        pq += __shfl_xor(pq, msk, 64);
      }
      if (r == 0) {
        int row = mi * 16 + q * 4 + i;
        red[wv][row][0] = ps; red[wv][row][1] = pq;
      }
    }
  __syncthreads();
  if (t < BME) {
    float s = red[0][t][0] + red[1][t][0] + red[2][t][0] + red[3][t][0];
    float sq = red[0][t][1] + red[1][t][1] + red[2][t][1] + red[3][t][1];
    float mean = s * (1.f / 256.f);
    float var = sq * (1.f / 256.f) - mean * mean;
    mr[t][0] = mean; mr[t][1] = rsqrtf(fmaxf(var, 0.f) + 1e-5f);
  }
  __syncthreads();
  // pass 2: normalize + relu + W2 partials
#pragma unroll
  for (int mi = 0; mi < 3; mi++)
#pragma unroll
    for (int i = 0; i < 4; i++) {
      int row = mi * 16 + q * 4 + i;
      float mean = mr[row][0], rstd = mr[row][1];
      float p0 = 0.f, p1 = 0.f;
#pragma unroll
      for (int ni = 0; ni < 4; ni++) {
        float x = acc[mi][ni][i] + b1v[ni];
        float y = (x - mean) * rstd * gv[ni] + bev[ni];
        y = fmaxf(y, 0.f);
        p0 += y * w20[ni]; p1 += y * w21[ni];
      }
      for (int msk = 1; msk < 16; msk <<= 1) {
        p0 += __shfl_xor(p0, msk, 64);
        p1 += __shfl_xor(p1, msk, 64);
      }
      if (r == 0) { red[wv][row][0] = p0; red[wv][row][1] = p1; }
    }
  __syncthreads();
  if (t < BME * 2) {
    int row = t >> 1, c = t & 1;
    float v = red[0][row][c] + red[1][row][c] + red[2][row][c] + red[3][row][c] + b2f(b2[c]);
    if (*flag) outEf[(size_t)(eb + row) * 2 + c] = v;
    else outE[(size_t)(eb + row) * 2 + c] = f2b(v);
  }
}

extern "C" void kernel_launch(void* const* d_in, const int* in_sizes, int n_in,
                              void* d_out, int out_size, void* d_ws, size_t ws_size,
                              hipStream_t stream) {
  char* wp = (char*)d_ws;
  auto alloc = [&](size_t bytes) -> char* {
    char* p = wp; wp += (bytes + 255) & ~(size_t)255; return p;
  };
  int* flag       = (int*)alloc(256);
  // canonical bf16 copies of all float inputs
  u16* c_h        = (u16*)alloc((size_t)N_NODES * 128 * 2);
  u16* c_ef       = (u16*)alloc((size_t)N_EDGES * 6 * 2);
  static const int pidx[20] = {4,5,6,7,8, 9,10,11,12, 13,14,15,16,17,18, 19,20,21,22,23};
  static const int pn[20]   = {16384,128,32768,256,32768, 1280,5,5,5,
                               135168,256,256,256,512,2, 65536,256,32768,128,32768};
  u16* cp[20];
  for (int a = 0; a < 20; a++) cp[a] = (u16*)alloc((size_t)pn[a] * 2);

  u16* wt_encpool = (u16*)alloc(128 * 128 * 2);
  u16* wt_enc     = (u16*)alloc(256 * 256 * 2);
  u16* wt_decpool = (u16*)alloc(256 * 256 * 2);
  u16* wt_dec     = (u16*)alloc(128 * 512 * 2);
  u16* wt_ep1     = (u16*)alloc(256 * 544 * 2);
  u16* m_buf      = (u16*)alloc((size_t)N_NODES * 256 * 2);  // aliased as aggb
  float* aggf     = (float*)alloc((size_t)N_NODES * 256 * 4);
  u16* h1b        = (u16*)alloc((size_t)N_NODES * 256 * 2);
  u16* smb        = (u16*)alloc((size_t)N_NODES * 5 * 2);
  u16* aggb       = m_buf;  // m_buf is dead by the time aggb is written

  const int* src = (const int*)d_in[2];
  const int* dst = (const int*)d_in[3];

  u16* outN = (u16*)d_out;
  u16* outE = outN + (size_t)N_NODES * 5;
  u16* outH = outN + 1110000;
  float* outNf = (float*)d_out;
  float* outEf = outNf + (size_t)N_NODES * 5;
  float* outHf = outNf + 1110000;

  // --- dtype sniff + input conversion ---
  sniff<<<1, 64, 0, stream>>>((const u16*)d_in[0], flag);
  conv_arr<<<15000, 256, 0, stream>>>(d_in[0], c_h, N_NODES * 128, flag);
  conv_arr<<<11250, 256, 0, stream>>>(d_in[1], c_ef, N_EDGES * 6, flag);
  ConvTab tab;
  int off = 0;
  for (int a = 0; a < 20; a++) {
    tab.e[a].s = d_in[pidx[a]]; tab.e[a].d = cp[a]; tab.e[a].n = pn[a]; tab.e[a].off = off;
    off += pn[a];
  }
  tab.total = off;
  conv_params<<<(off + 255) / 256, 256, 0, stream>>>(tab, flag);

  const u16 *enc_Wpool = cp[0], *enc_bpool = cp[1], *enc_Wself = cp[2], *enc_bself = cp[3],
            *enc_Wneigh = cp[4], *np_W = cp[5], *np_b = cp[6], *np_g = cp[7], *np_beta = cp[8],
            *ep_W1 = cp[9], *ep_b1 = cp[10], *ep_g = cp[11], *ep_beta = cp[12],
            *ep_W2 = cp[13], *ep_b2 = cp[14], *dec_Wpool = cp[15], *dec_bpool = cp[16],
            *dec_Wself = cp[17], *dec_bself = cp[18], *dec_Wneigh = cp[19];

  // --- weight prep ---
  transpose_k<<<64, 256, 0, stream>>>(enc_Wpool, wt_encpool, 128, 7, 128, 0);
  transpose_k<<<128, 256, 0, stream>>>(enc_Wself, wt_enc, 128, 8, 256, 0);
  transpose_k<<<128, 256, 0, stream>>>(enc_Wneigh, wt_enc, 128, 8, 256, 128);
  transpose_k<<<256, 256, 0, stream>>>(dec_Wpool, wt_decpool, 256, 8, 256, 0);
  transpose_k<<<128, 256, 0, stream>>>(dec_Wself, wt_dec, 256, 7, 512, 0);
  transpose_k<<<128, 256, 0, stream>>>(dec_Wneigh, wt_dec, 256, 7, 512, 256);
  build_wt1<<<256, 256, 0, stream>>>(ep_W1, wt_ep1);

  // --- encoder ---
  hipMemsetAsync(aggf, 0, (size_t)N_NODES * 128 * 4, stream);
  gemm_mfma<<<dim3(235, 1), 256, 0, stream>>>(c_h, nullptr, 128, 0, wt_encpool,
                                              enc_bpool, m_buf, nullptr, flag, N_NODES, 128);
  scatter_max<<<60000, 256, 0, stream>>>(m_buf, src, dst, aggf, 5, N_EDGES);
  f32_to_b16<<<15000, 256, 0, stream>>>(aggf, aggb, N_NODES * 128);
  gemm_mfma<<<dim3(235, 2), 256, 0, stream>>>(c_h, aggb, 128, 128, wt_enc,
                                              enc_bself, h1b, nullptr, flag, N_NODES, 256);
  // --- node head ---
  node_head<<<118, 256, 0, stream>>>(h1b, np_W, np_b, np_g, np_beta, outN, outNf, flag, smb);
  // --- edge head ---
  edge_mlp<<<N_EDGES / BME, 256, 0, stream>>>(h1b, smb, c_ef, src, dst, wt_ep1,
                                              ep_b1, ep_g, ep_beta, ep_W2, ep_b2,
                                              outE, outEf, flag);
  // --- decoder ---
  gemm_mfma<<<dim3(235, 2), 256, 0, stream>>>(h1b, nullptr, 256, 0, wt_decpool,
                                              dec_bpool, m_buf, nullptr, flag, N_NODES, 256);
  hipMemsetAsync(aggf, 0, (size_t)N_NODES * 256 * 4, stream);
  scatter_max<<<120000, 256, 0, stream>>>(m_buf, src, dst, aggf, 6, N_EDGES);
  f32_to_b16<<<30000, 256, 0, stream>>>(aggf, aggb, N_NODES * 256);
  gemm_mfma<<<dim3(235, 1), 256, 0, stream>>>(h1b, aggb, 256, 256, wt_dec,
                                              dec_bself, outH, outHf, flag, N_NODES, 128);
}

// Round 3
// 789.775 us; speedup vs baseline: 1.8078x; 1.8078x over previous
//
#include <hip/hip_runtime.h>

typedef unsigned short u16;
typedef unsigned int u32;
typedef __bf16 bf16_t;
typedef bf16_t bf16x8 __attribute__((ext_vector_type(8)));
typedef float f32x4 __attribute__((ext_vector_type(4)));

#define N_NODES 30000
#define N_EDGES 480000
#define BME 48  // edges per block in edge_mlp

static __device__ __forceinline__ float b2f(u16 u) {
  return __uint_as_float(((u32)u) << 16);
}
static __device__ __forceinline__ float b2f_lo(u32 w) {
  return __uint_as_float(w << 16);
}
static __device__ __forceinline__ float b2f_hi(u32 w) {
  return __uint_as_float(w & 0xffff0000u);
}
static __device__ __forceinline__ u16 f2b(float f) {
  u32 x = __float_as_uint(f);
  u32 r = (x + 0x7fffu + ((x >> 16) & 1u)) >> 16;
  return (u16)r;
}

// ---------------- dtype sniff: bf16 storage (flag=0) vs f32 storage (flag=1) ----------------
__global__ void sniff(const u16* __restrict__ h, int* __restrict__ flag) {
  int t = threadIdx.x;
  int bad = 0;
#pragma unroll
  for (int i = 0; i < 4; i++) {
    u32 e = ((u32)h[t * 4 + i] >> 7) & 0xFFu;
    if (e >= 0x8Eu) bad = 1;  // impossible magnitude for N(0,1) bf16 data
  }
  int r = __syncthreads_or(bad);
  if (t == 0) *flag = r ? 1 : 0;
}

// ---------------- convert one big array to canonical bf16 ----------------
__global__ __launch_bounds__(256) void conv_arr(const void* __restrict__ src,
                                                u16* __restrict__ dst, int n,
                                                const int* __restrict__ flag) {
  int i = blockIdx.x * 256 + threadIdx.x;
  if (i >= n) return;
  if (*flag) dst[i] = f2b(((const float*)src)[i]);
  else dst[i] = ((const u16*)src)[i];
}

struct ConvDesc { const void* s; u16* d; int n; int off; };
struct ConvTab { ConvDesc e[20]; int total; };

__global__ __launch_bounds__(256) void conv_params(ConvTab tab, const int* __restrict__ flag) {
  int i = blockIdx.x * 256 + threadIdx.x;
  if (i >= tab.total) return;
  int f = *flag;
#pragma unroll 1
  for (int a = 0; a < 20; a++) {
    int j = i - tab.e[a].off;
    if (j >= 0 && j < tab.e[a].n) {
      if (f) tab.e[a].d[j] = f2b(((const float*)tab.e[a].s)[j]);
      else tab.e[a].d[j] = ((const u16*)tab.e[a].s)[j];
      return;
    }
  }
}

// ---------------- CSR build: deg -> off (scan) -> fill ----------------
__global__ __launch_bounds__(256) void deg_count(const int* __restrict__ dst,
                                                 int* __restrict__ deg, int nE) {
  int e = blockIdx.x * 256 + threadIdx.x;
  if (e < nE) atomicAdd(&deg[dst[e]], 1);
}

__global__ __launch_bounds__(256) void scan_off(const int* __restrict__ deg,
                                                int* __restrict__ off, int n) {
  __shared__ int carry;
  __shared__ int wsum[4];
  int t = threadIdx.x, lane = t & 63, wv = t >> 6;
  if (t == 0) { carry = 0; off[0] = 0; }
  __syncthreads();
  for (int base = 0; base < n; base += 256) {
    int v = (base + t < n) ? deg[base + t] : 0;
    int x = v;
#pragma unroll
    for (int d = 1; d < 64; d <<= 1) {
      int y = __shfl_up(x, d, 64);
      if (lane >= d) x += y;
    }
    if (lane == 63) wsum[wv] = x;
    __syncthreads();
    int wadd = 0;
    for (int w = 0; w < wv; w++) wadd += wsum[w];
    int incl = x + wadd + carry;
    if (base + t < n) off[base + t + 1] = incl;
    __syncthreads();
    if (t == 255) carry = incl;
    __syncthreads();
  }
}

__global__ __launch_bounds__(256) void fill_csr(const int* __restrict__ src,
                                                const int* __restrict__ dst,
                                                int* __restrict__ cursor,
                                                int* __restrict__ esrc, int nE) {
  int e = blockIdx.x * 256 + threadIdx.x;
  if (e >= nE) return;
  int p = atomicAdd(&cursor[dst[e]], 1);
  esrc[p] = src[e];
}

// ---------------- CSR max-aggregate: out[n] = max over in-edges of m[src] (bf16, >=0) ----------------
// Unsigned compare on raw u16 == float compare for non-negative bf16.
__global__ __launch_bounds__(256) void agg128(const u16* __restrict__ m,
                                              const int* __restrict__ esrc,
                                              const int* __restrict__ off,
                                              u16* __restrict__ out) {
  int wv = threadIdx.x >> 6, lane = threadIdx.x & 63;
  int n = blockIdx.x * 4 + wv;
  if (n >= N_NODES) return;
  int s0 = off[n], s1 = off[n + 1];
  u32 a0 = 0, a1 = 0;
  int i = s0;
  for (; i + 1 < s1; i += 2) {
    int sa = esrc[i], sb = esrc[i + 1];
    u32 ra = *(const u32*)(m + (size_t)sa * 128 + lane * 2);
    u32 rb = *(const u32*)(m + (size_t)sb * 128 + lane * 2);
    a0 = max(a0, ra & 0xffffu); a1 = max(a1, ra >> 16);
    a0 = max(a0, rb & 0xffffu); a1 = max(a1, rb >> 16);
  }
  if (i < s1) {
    u32 ra = *(const u32*)(m + (size_t)esrc[i] * 128 + lane * 2);
    a0 = max(a0, ra & 0xffffu); a1 = max(a1, ra >> 16);
  }
  *(u32*)(out + (size_t)n * 128 + lane * 2) = a0 | (a1 << 16);
}

__global__ __launch_bounds__(256) void agg256(const u16* __restrict__ m,
                                              const int* __restrict__ esrc,
                                              const int* __restrict__ off,
                                              u16* __restrict__ out) {
  int wv = threadIdx.x >> 6, lane = threadIdx.x & 63;
  int n = blockIdx.x * 4 + wv;
  if (n >= N_NODES) return;
  int s0 = off[n], s1 = off[n + 1];
  u32 a0 = 0, a1 = 0, a2 = 0, a3 = 0;
  int i = s0;
  for (; i + 1 < s1; i += 2) {
    int sa = esrc[i], sb = esrc[i + 1];
    uint2 ra = *(const uint2*)(m + (size_t)sa * 256 + lane * 4);
    uint2 rb = *(const uint2*)(m + (size_t)sb * 256 + lane * 4);
    a0 = max(a0, ra.x & 0xffffu); a1 = max(a1, ra.x >> 16);
    a2 = max(a2, ra.y & 0xffffu); a3 = max(a3, ra.y >> 16);
    a0 = max(a0, rb.x & 0xffffu); a1 = max(a1, rb.x >> 16);
    a2 = max(a2, rb.y & 0xffffu); a3 = max(a3, rb.y >> 16);
  }
  if (i < s1) {
    uint2 ra = *(const uint2*)(m + (size_t)esrc[i] * 256 + lane * 4);
    a0 = max(a0, ra.x & 0xffffu); a1 = max(a1, ra.x >> 16);
    a2 = max(a2, ra.y & 0xffffu); a3 = max(a3, ra.y >> 16);
  }
  uint2 w;
  w.x = a0 | (a1 << 16);
  w.y = a2 | (a3 << 16);
  *(uint2*)(out + (size_t)n * 256 + lane * 4) = w;
}

// ---------------- weight transpose: dst[n*ldo + ko + k] = src[k*Nn + n] ----------------
__global__ void transpose_k(const u16* __restrict__ src, u16* __restrict__ dstp,
                            int K, int nshift, int ldo, int ko) {
  int tid = blockIdx.x * 256 + threadIdx.x;
  int Nn = 1 << nshift;
  int k = tid >> nshift, n = tid & (Nn - 1);
  if (k >= K) return;
  dstp[(size_t)n * ldo + ko + k] = src[(size_t)k * Nn + n];
}

// ---------------- build permuted+padded ep_W1^T: [256 n][544 k'] ----------------
__global__ void build_wt1(const u16* __restrict__ w1, u16* __restrict__ dstp) {
  int n = blockIdx.x;  // 0..255
  for (int kp = threadIdx.x; kp < 544; kp += 256) {
    u16 v = 0;
    int ro = -1;
    if (kp < 256) ro = kp;                       // h1[src]
    else if (kp < 512) ro = 267 + (kp - 256);    // h1[dst]
    else if (kp < 517) ro = 256 + (kp - 512);    // sm[src]
    else if (kp < 522) ro = 523 + (kp - 517);    // sm[dst]
    else if (kp < 528) ro = 261 + (kp - 522);    // efeat
    if (ro >= 0) v = w1[(size_t)ro * 256 + n];
    dstp[(size_t)n * 544 + kp] = v;
  }
}

// ---------------- generic MFMA GEMM: C = relu(concat(A0,A1) @ Bt^T + bias) ----------------
__global__ __launch_bounds__(256) void gemm_mfma(
    const u16* __restrict__ A0, const u16* __restrict__ A1, int K0, int K1,
    const u16* __restrict__ Bt, const u16* __restrict__ bias,
    u16* __restrict__ C, float* __restrict__ Cf, const int* __restrict__ flag,
    int M, int Nld) {
  __shared__ __align__(16) u16 As[128 * 40];
  __shared__ __align__(16) u16 Bs[128 * 40];
  const int t = threadIdx.x;
  const int lane = t & 63, wv = t >> 6;
  const int wm = wv & 1, wn = wv >> 1;
  const int r = lane & 15, q = lane >> 4;
  const int bm = blockIdx.x, bn = blockIdx.y;
  const int Ktot = K0 + K1;
  const bool usef = (Cf != nullptr) && (*flag != 0);

  f32x4 acc[4][4];
#pragma unroll
  for (int i = 0; i < 4; i++)
#pragma unroll
    for (int j = 0; j < 4; j++) acc[i][j] = (f32x4){0.f, 0.f, 0.f, 0.f};

  for (int kc = 0; kc < Ktot; kc += 32) {
#pragma unroll
    for (int h = 0; h < 2; h++) {
      int idx = t + h * 256;          // 0..511
      int rr = idx >> 2, qq = idx & 3;
      int rowg = bm * 128 + rr;
      uint4 av = make_uint4(0, 0, 0, 0);
      if (rowg < M) {
        const u16* p = (kc < K0) ? (A0 + (size_t)rowg * K0 + kc)
                                 : (A1 + (size_t)rowg * K1 + (kc - K0));
        av = *(const uint4*)(p + qq * 8);
      }
      *(uint4*)&As[rr * 40 + qq * 8] = av;
      int ng = bn * 128 + rr;
      uint4 bv = *(const uint4*)(Bt + (size_t)ng * Ktot + kc + qq * 8);
      *(uint4*)&Bs[rr * 40 + qq * 8] = bv;
    }
    __syncthreads();
    bf16x8 af[4], bfm[4];
#pragma unroll
    for (int mi = 0; mi < 4; mi++)
      af[mi] = *(const bf16x8*)&As[(wm * 64 + mi * 16 + r) * 40 + q * 8];
#pragma unroll
    for (int ni = 0; ni < 4; ni++)
      bfm[ni] = *(const bf16x8*)&Bs[(wn * 64 + ni * 16 + r) * 40 + q * 8];
#pragma unroll
    for (int mi = 0; mi < 4; mi++)
#pragma unroll
      for (int ni = 0; ni < 4; ni++)
        acc[mi][ni] = __builtin_amdgcn_mfma_f32_16x16x32_bf16(af[mi], bfm[ni], acc[mi][ni], 0, 0, 0);
    __syncthreads();
  }

  float bv[4];
#pragma unroll
  for (int ni = 0; ni < 4; ni++) bv[ni] = b2f(bias[bn * 128 + wn * 64 + ni * 16 + r]);
#pragma unroll
  for (int mi = 0; mi < 4; mi++) {
#pragma unroll
    for (int i = 0; i < 4; i++) {
      int rowg = bm * 128 + wm * 64 + mi * 16 + q * 4 + i;
      if (rowg >= M) continue;
#pragma unroll
      for (int ni = 0; ni < 4; ni++) {
        int colg = bn * 128 + wn * 64 + ni * 16 + r;
        float v = acc[mi][ni][i] + bv[ni];
        v = v > 0.f ? v : 0.f;
        if (usef) Cf[(size_t)rowg * Nld + colg] = v;
        else C[(size_t)rowg * Nld + colg] = f2b(v);
      }
    }
  }
}

// ---------------- node head: node_pred = LN(h1@W + b), sm = softmax(node_pred) ----------------
__global__ __launch_bounds__(256) void node_head(
    const u16* __restrict__ h1, const u16* __restrict__ W, const u16* __restrict__ b,
    const u16* __restrict__ g, const u16* __restrict__ beta,
    u16* __restrict__ outN, float* __restrict__ outNf, const int* __restrict__ flag,
    u16* __restrict__ smOut) {
  __shared__ float Wl[256 * 5];
  __shared__ float bl[5], gl[5], betal[5];
  int t = threadIdx.x;
#pragma unroll
  for (int c = 0; c < 5; c++) Wl[t * 5 + c] = b2f(W[t * 5 + c]);
  if (t < 5) { bl[t] = b2f(b[t]); gl[t] = b2f(g[t]); betal[t] = b2f(beta[t]); }
  __syncthreads();
  int n = blockIdx.x * 256 + t;
  if (n >= N_NODES) return;
  const bool usef = (*flag != 0);
  float acc[5] = {0.f, 0.f, 0.f, 0.f, 0.f};
  const u16* hp = h1 + (size_t)n * 256;
  for (int k8 = 0; k8 < 32; k8++) {
    uint4 v = *(const uint4*)(hp + k8 * 8);
    u32 wds[4] = {v.x, v.y, v.z, v.w};
#pragma unroll
    for (int h = 0; h < 4; h++) {
      float x0 = b2f_lo(wds[h]), x1 = b2f_hi(wds[h]);
      int k = k8 * 8 + h * 2;
#pragma unroll
      for (int c = 0; c < 5; c++)
        acc[c] += x0 * Wl[k * 5 + c] + x1 * Wl[(k + 1) * 5 + c];
    }
  }
  float x[5], mu = 0.f;
#pragma unroll
  for (int c = 0; c < 5; c++) { x[c] = acc[c] + bl[c]; mu += x[c]; }
  mu *= 0.2f;
  float var = 0.f;
#pragma unroll
  for (int c = 0; c < 5; c++) { float d = x[c] - mu; var += d * d; }
  var *= 0.2f;
  float rstd = rsqrtf(fmaxf(var, 0.f) + 1e-5f);
  float v5[5], mx = -1e30f;
#pragma unroll
  for (int c = 0; c < 5; c++) {
    v5[c] = gl[c] * (x[c] - mu) * rstd + betal[c];
    if (usef) outNf[(size_t)n * 5 + c] = v5[c];
    else outN[(size_t)n * 5 + c] = f2b(v5[c]);
    mx = fmaxf(mx, v5[c]);
  }
  float s = 0.f, ex[5];
#pragma unroll
  for (int c = 0; c < 5; c++) { ex[c] = __expf(v5[c] - mx); s += ex[c]; }
  float inv = 1.f / s;
#pragma unroll
  for (int c = 0; c < 5; c++) smOut[(size_t)n * 5 + c] = f2b(ex[c] * inv);
}

// ---------------- fused edge MLP: gather-concat -> @W1+b1 -> LN -> relu -> @W2+b2 ----------------
__global__ __launch_bounds__(256) void edge_mlp(
    const u16* __restrict__ h1, const u16* __restrict__ sm, const u16* __restrict__ ef,
    const int* __restrict__ src, const int* __restrict__ dst,
    const u16* __restrict__ wt1, const u16* __restrict__ b1,
    const u16* __restrict__ g, const u16* __restrict__ beta,
    const u16* __restrict__ w2, const u16* __restrict__ b2,
    u16* __restrict__ outE, float* __restrict__ outEf, const int* __restrict__ flag) {
  __shared__ __align__(16) u16 Ax[BME * 552];  // 48 rows x 544(+8 pad) bf16
  __shared__ int sidx[BME], didx[BME];
  __shared__ float red[4][BME][2];
  __shared__ float mr[BME][2];
  const int t = threadIdx.x;
  const int eb = blockIdx.x * BME;
  if (t < BME) { sidx[t] = src[eb + t]; didx[t] = dst[eb + t]; }
  __syncthreads();
#pragma unroll
  for (int i = 0; i < 6; i++) {
    int c = t + i * 256;  // 0..1535
    int e = c >> 5, qq = c & 31;
    uint4 v = *(const uint4*)(h1 + (size_t)sidx[e] * 256 + qq * 8);
    *(uint4*)&Ax[e * 552 + qq * 8] = v;
    uint4 w = *(const uint4*)(h1 + (size_t)didx[e] * 256 + qq * 8);
    *(uint4*)&Ax[e * 552 + 256 + qq * 8] = w;
  }
  if (t < BME * 4) {
    int e = t >> 2, j0 = (t & 3) * 8;
#pragma unroll
    for (int jj = 0; jj < 8; jj++) {
      int j = j0 + jj;
      u16 val = 0;
      if (j < 5) val = sm[(size_t)sidx[e] * 5 + j];
      else if (j < 10) val = sm[(size_t)didx[e] * 5 + (j - 5)];
      else if (j < 16) val = ef[(size_t)(eb + e) * 6 + (j - 10)];
      Ax[e * 552 + 512 + j] = val;
    }
  }
  __syncthreads();

  const int lane = t & 63, wv = t >> 6;
  const int r = lane & 15, q = lane >> 4;
  f32x4 acc[3][4];
#pragma unroll
  for (int mi = 0; mi < 3; mi++)
#pragma unroll
    for (int ni = 0; ni < 4; ni++) acc[mi][ni] = (f32x4){0.f, 0.f, 0.f, 0.f};

  int ncol[4];
#pragma unroll
  for (int ni = 0; ni < 4; ni++) ncol[ni] = wv * 64 + ni * 16 + r;
  uint4 braw[4], bnext[4];
#pragma unroll
  for (int ni = 0; ni < 4; ni++)
    braw[ni] = *(const uint4*)(wt1 + (size_t)ncol[ni] * 544 + q * 8);

  for (int kc = 0; kc < 544; kc += 32) {
    bf16x8 af[3];
#pragma unroll
    for (int mi = 0; mi < 3; mi++)
      af[mi] = *(const bf16x8*)&Ax[(mi * 16 + r) * 552 + kc + q * 8];
    if (kc + 32 < 544) {
#pragma unroll
      for (int ni = 0; ni < 4; ni++)
        bnext[ni] = *(const uint4*)(wt1 + (size_t)ncol[ni] * 544 + (kc + 32) + q * 8);
    }
#pragma unroll
    for (int mi = 0; mi < 3; mi++)
#pragma unroll
      for (int ni = 0; ni < 4; ni++)
        acc[mi][ni] = __builtin_amdgcn_mfma_f32_16x16x32_bf16(
            af[mi], __builtin_bit_cast(bf16x8, braw[ni]), acc[mi][ni], 0, 0, 0);
#pragma unroll
    for (int ni = 0; ni < 4; ni++) braw[ni] = bnext[ni];
  }

  float b1v[4], gv[4], bev[4], w20[4], w21[4];
#pragma unroll
  for (int ni = 0; ni < 4; ni++) {
    int c = ncol[ni];
    b1v[ni] = b2f(b1[c]); gv[ni] = b2f(g[c]); bev[ni] = b2f(beta[c]);
    w20[ni] = b2f(w2[c * 2]); w21[ni] = b2f(w2[c * 2 + 1]);
  }
  // pass 1: LN stats (sum, sumsq over 256 cols per edge row)
#pragma unroll
  for (int mi = 0; mi < 3; mi++)
#pragma unroll
    for (int i = 0; i < 4; i++) {
      float ps = 0.f, pq = 0.f;
#pragma unroll
      for (int ni = 0; ni < 4; ni++) {
        float x = acc[mi][ni][i] + b1v[ni];
        ps += x; pq += x * x;
      }
      for (int msk = 1; msk < 16; msk <<= 1) {
        ps += __shfl_xor(ps, msk, 64);
        pq += __shfl_xor(pq, msk, 64);
      }
      if (r == 0) {
        int row = mi * 16 + q * 4 + i;
        red[wv][row][0] = ps; red[wv][row][1] = pq;
      }
    }
  __syncthreads();
  if (t < BME) {
    float s = red[0][t][0] + red[1][t][0] + red[2][t][0] + red[3][t][0];
    float sq = red[0][t][1] + red[1][t][1] + red[2][t][1] + red[3][t][1];
    float mean = s * (1.f / 256.f);
    float var = sq * (1.f / 256.f) - mean * mean;
    mr[t][0] = mean; mr[t][1] = rsqrtf(fmaxf(var, 0.f) + 1e-5f);
  }
  __syncthreads();
  // pass 2: normalize + relu + W2 partials
#pragma unroll
  for (int mi = 0; mi < 3; mi++)
#pragma unroll
    for (int i = 0; i < 4; i++) {
      int row = mi * 16 + q * 4 + i;
      float mean = mr[row][0], rstd = mr[row][1];
      float p0 = 0.f, p1 = 0.f;
#pragma unroll
      for (int ni = 0; ni < 4; ni++) {
        float x = acc[mi][ni][i] + b1v[ni];
        float y = (x - mean) * rstd * gv[ni] + bev[ni];
        y = fmaxf(y, 0.f);
        p0 += y * w20[ni]; p1 += y * w21[ni];
      }
      for (int msk = 1; msk < 16; msk <<= 1) {
        p0 += __shfl_xor(p0, msk, 64);
        p1 += __shfl_xor(p1, msk, 64);
      }
      if (r == 0) { red[wv][row][0] = p0; red[wv][row][1] = p1; }
    }
  __syncthreads();
  if (t < BME * 2) {
    int row = t >> 1, c = t & 1;
    float v = red[0][row][c] + red[1][row][c] + red[2][row][c] + red[3][row][c] + b2f(b2[c]);
    if (*flag) outEf[(size_t)(eb + row) * 2 + c] = v;
    else outE[(size_t)(eb + row) * 2 + c] = f2b(v);
  }
}

extern "C" void kernel_launch(void* const* d_in, const int* in_sizes, int n_in,
                              void* d_out, int out_size, void* d_ws, size_t ws_size,
                              hipStream_t stream) {
  char* wp = (char*)d_ws;
  auto alloc = [&](size_t bytes) -> char* {
    char* p = wp; wp += (bytes + 255) & ~(size_t)255; return p;
  };
  int* flag       = (int*)alloc(256);
  // canonical bf16 copies of all float inputs
  u16* c_h        = (u16*)alloc((size_t)N_NODES * 128 * 2);
  u16* c_ef       = (u16*)alloc((size_t)N_EDGES * 6 * 2);
  static const int pidx[20] = {4,5,6,7,8, 9,10,11,12, 13,14,15,16,17,18, 19,20,21,22,23};
  static const int pn[20]   = {16384,128,32768,256,32768, 1280,5,5,5,
                               135168,256,256,256,512,2, 65536,256,32768,128,32768};
  u16* cp[20];
  for (int a = 0; a < 20; a++) cp[a] = (u16*)alloc((size_t)pn[a] * 2);

  u16* wt_encpool = (u16*)alloc(128 * 128 * 2);
  u16* wt_enc     = (u16*)alloc(256 * 256 * 2);
  u16* wt_decpool = (u16*)alloc(256 * 256 * 2);
  u16* wt_dec     = (u16*)alloc(128 * 512 * 2);
  u16* wt_ep1     = (u16*)alloc(256 * 544 * 2);
  u16* m_buf      = (u16*)alloc((size_t)N_NODES * 256 * 2);
  u16* aggb       = (u16*)alloc((size_t)N_NODES * 256 * 2);
  u16* h1b        = (u16*)alloc((size_t)N_NODES * 256 * 2);
  u16* smb        = (u16*)alloc((size_t)N_NODES * 5 * 2);
  // CSR
  int* deg        = (int*)alloc((size_t)N_NODES * 4);
  int* off        = (int*)alloc((size_t)(N_NODES + 1) * 4);
  int* cursor     = (int*)alloc((size_t)N_NODES * 4);
  int* esrc       = (int*)alloc((size_t)N_EDGES * 4);

  const int* src = (const int*)d_in[2];
  const int* dst = (const int*)d_in[3];

  u16* outN = (u16*)d_out;
  u16* outE = outN + (size_t)N_NODES * 5;
  u16* outH = outN + 1110000;
  float* outNf = (float*)d_out;
  float* outEf = outNf + (size_t)N_NODES * 5;
  float* outHf = outNf + 1110000;

  // --- dtype sniff + input conversion ---
  sniff<<<1, 256, 0, stream>>>((const u16*)d_in[0], flag);
  conv_arr<<<15000, 256, 0, stream>>>(d_in[0], c_h, N_NODES * 128, flag);
  conv_arr<<<11250, 256, 0, stream>>>(d_in[1], c_ef, N_EDGES * 6, flag);
  ConvTab tab;
  int off_a = 0;
  for (int a = 0; a < 20; a++) {
    tab.e[a].s = d_in[pidx[a]]; tab.e[a].d = cp[a]; tab.e[a].n = pn[a]; tab.e[a].off = off_a;
    off_a += pn[a];
  }
  tab.total = off_a;
  conv_params<<<(off_a + 255) / 256, 256, 0, stream>>>(tab, flag);

  const u16 *enc_Wpool = cp[0], *enc_bpool = cp[1], *enc_Wself = cp[2], *enc_bself = cp[3],
            *enc_Wneigh = cp[4], *np_W = cp[5], *np_b = cp[6], *np_g = cp[7], *np_beta = cp[8],
            *ep_W1 = cp[9], *ep_b1 = cp[10], *ep_g = cp[11], *ep_beta = cp[12],
            *ep_W2 = cp[13], *ep_b2 = cp[14], *dec_Wpool = cp[15], *dec_bpool = cp[16],
            *dec_Wself = cp[17], *dec_bself = cp[18], *dec_Wneigh = cp[19];

  // --- CSR build (shared by both aggregations) ---
  hipMemsetAsync(deg, 0, (size_t)N_NODES * 4, stream);
  deg_count<<<1875, 256, 0, stream>>>(dst, deg, N_EDGES);
  scan_off<<<1, 256, 0, stream>>>(deg, off, N_NODES);
  hipMemcpyAsync(cursor, off, (size_t)N_NODES * 4, hipMemcpyDeviceToDevice, stream);
  fill_csr<<<1875, 256, 0, stream>>>(src, dst, cursor, esrc, N_EDGES);

  // --- weight prep ---
  transpose_k<<<64, 256, 0, stream>>>(enc_Wpool, wt_encpool, 128, 7, 128, 0);
  transpose_k<<<128, 256, 0, stream>>>(enc_Wself, wt_enc, 128, 8, 256, 0);
  transpose_k<<<128, 256, 0, stream>>>(enc_Wneigh, wt_enc, 128, 8, 256, 128);
  transpose_k<<<256, 256, 0, stream>>>(dec_Wpool, wt_decpool, 256, 8, 256, 0);
  transpose_k<<<128, 256, 0, stream>>>(dec_Wself, wt_dec, 256, 7, 512, 0);
  transpose_k<<<128, 256, 0, stream>>>(dec_Wneigh, wt_dec, 256, 7, 512, 256);
  build_wt1<<<256, 256, 0, stream>>>(ep_W1, wt_ep1);

  // --- encoder ---
  gemm_mfma<<<dim3(235, 1), 256, 0, stream>>>(c_h, nullptr, 128, 0, wt_encpool,
                                              enc_bpool, m_buf, nullptr, flag, N_NODES, 128);
  agg128<<<7500, 256, 0, stream>>>(m_buf, esrc, off, aggb);
  gemm_mfma<<<dim3(235, 2), 256, 0, stream>>>(c_h, aggb, 128, 128, wt_enc,
                                              enc_bself, h1b, nullptr, flag, N_NODES, 256);
  // --- node head ---
  node_head<<<118, 256, 0, stream>>>(h1b, np_W, np_b, np_g, np_beta, outN, outNf, flag, smb);
  // --- edge head ---
  edge_mlp<<<N_EDGES / BME, 256, 0, stream>>>(h1b, smb, c_ef, src, dst, wt_ep1,
                                              ep_b1, ep_g, ep_beta, ep_W2, ep_b2,
                                              outE, outEf, flag);
  // --- decoder ---
  gemm_mfma<<<dim3(235, 2), 256, 0, stream>>>(h1b, nullptr, 256, 0, wt_decpool,
                                              dec_bpool, m_buf, nullptr, flag, N_NODES, 256);
  agg256<<<7500, 256, 0, stream>>>(m_buf, esrc, off, aggb);
  gemm_mfma<<<dim3(235, 1), 256, 0, stream>>>(h1b, aggb, 256, 256, wt_dec,
                                              dec_bself, outH, outHf, flag, N_NODES, 128);
}

// Round 4
// 713.153 us; speedup vs baseline: 2.0020x; 1.1074x over previous
//
#include <hip/hip_runtime.h>

typedef unsigned short u16;
typedef unsigned int u32;
typedef __bf16 bf16_t;
typedef bf16_t bf16x8 __attribute__((ext_vector_type(8)));
typedef float f32x4 __attribute__((ext_vector_type(4)));

#define N_NODES 30000
#define N_EDGES 480000

static __device__ __forceinline__ float b2f(u16 u) {
  return __uint_as_float(((u32)u) << 16);
}
static __device__ __forceinline__ float b2f_lo(u32 w) {
  return __uint_as_float(w << 16);
}
static __device__ __forceinline__ float b2f_hi(u32 w) {
  return __uint_as_float(w & 0xffff0000u);
}
static __device__ __forceinline__ u16 f2b(float f) {
  u32 x = __float_as_uint(f);
  u32 r = (x + 0x7fffu + ((x >> 16) & 1u)) >> 16;
  return (u16)r;
}

// ---------------- dtype sniff: bf16 storage (flag=0) vs f32 storage (flag=1) ----------------
__global__ void sniff(const u16* __restrict__ h, int* __restrict__ flag) {
  int t = threadIdx.x;
  int bad = 0;
#pragma unroll
  for (int i = 0; i < 4; i++) {
    u32 e = ((u32)h[t * 4 + i] >> 7) & 0xFFu;
    if (e >= 0x8Eu) bad = 1;  // impossible magnitude for N(0,1) bf16 data
  }
  int r = __syncthreads_or(bad);
  if (t == 0) *flag = r ? 1 : 0;
}

// ---------------- convert one big array to canonical bf16 ----------------
__global__ __launch_bounds__(256) void conv_arr(const void* __restrict__ src,
                                                u16* __restrict__ dst, int n,
                                                const int* __restrict__ flag) {
  int i = blockIdx.x * 256 + threadIdx.x;
  if (i >= n) return;
  if (*flag) dst[i] = f2b(((const float*)src)[i]);
  else dst[i] = ((const u16*)src)[i];
}

struct ConvDesc { const void* s; u16* d; int n; int off; };
struct ConvTab { ConvDesc e[20]; int total; };

__global__ __launch_bounds__(256) void conv_params(ConvTab tab, const int* __restrict__ flag) {
  int i = blockIdx.x * 256 + threadIdx.x;
  if (i >= tab.total) return;
  int f = *flag;
#pragma unroll 1
  for (int a = 0; a < 20; a++) {
    int j = i - tab.e[a].off;
    if (j >= 0 && j < tab.e[a].n) {
      if (f) tab.e[a].d[j] = f2b(((const float*)tab.e[a].s)[j]);
      else tab.e[a].d[j] = ((const u16*)tab.e[a].s)[j];
      return;
    }
  }
}

// ---------------- CSR build: deg -> off (scan) -> fill ----------------
__global__ __launch_bounds__(256) void deg_count(const int* __restrict__ dst,
                                                 int* __restrict__ deg, int nE) {
  int e = blockIdx.x * 256 + threadIdx.x;
  if (e < nE) atomicAdd(&deg[dst[e]], 1);
}

__global__ __launch_bounds__(256) void scan_off(const int* __restrict__ deg,
                                                int* __restrict__ off, int n) {
  __shared__ int carry;
  __shared__ int wsum[4];
  int t = threadIdx.x, lane = t & 63, wv = t >> 6;
  if (t == 0) { carry = 0; off[0] = 0; }
  __syncthreads();
  for (int base = 0; base < n; base += 256) {
    int v = (base + t < n) ? deg[base + t] : 0;
    int x = v;
#pragma unroll
    for (int d = 1; d < 64; d <<= 1) {
      int y = __shfl_up(x, d, 64);
      if (lane >= d) x += y;
    }
    if (lane == 63) wsum[wv] = x;
    __syncthreads();
    int wadd = 0;
    for (int w = 0; w < wv; w++) wadd += wsum[w];
    int incl = x + wadd + carry;
    if (base + t < n) off[base + t + 1] = incl;
    __syncthreads();
    if (t == 255) carry = incl;
    __syncthreads();
  }
}

__global__ __launch_bounds__(256) void fill_csr(const int* __restrict__ src,
                                                const int* __restrict__ dst,
                                                int* __restrict__ cursor,
                                                int* __restrict__ esrc, int nE) {
  int e = blockIdx.x * 256 + threadIdx.x;
  if (e >= nE) return;
  int p = atomicAdd(&cursor[dst[e]], 1);
  esrc[p] = src[e];
}

// ---------------- CSR max-aggregate: out[n] = max over in-edges of m[src] (bf16, >=0) ----------------
// Unsigned compare on raw u16 == float compare for non-negative bf16.
__global__ __launch_bounds__(256) void agg128(const u16* __restrict__ m,
                                              const int* __restrict__ esrc,
                                              const int* __restrict__ off,
                                              u16* __restrict__ out) {
  int wv = threadIdx.x >> 6, lane = threadIdx.x & 63;
  int n = blockIdx.x * 4 + wv;
  if (n >= N_NODES) return;
  int s0 = off[n], s1 = off[n + 1];
  u32 a0 = 0, a1 = 0;
  int i = s0;
  for (; i + 1 < s1; i += 2) {
    int sa = esrc[i], sb = esrc[i + 1];
    u32 ra = *(const u32*)(m + (size_t)sa * 128 + lane * 2);
    u32 rb = *(const u32*)(m + (size_t)sb * 128 + lane * 2);
    a0 = max(a0, ra & 0xffffu); a1 = max(a1, ra >> 16);
    a0 = max(a0, rb & 0xffffu); a1 = max(a1, rb >> 16);
  }
  if (i < s1) {
    u32 ra = *(const u32*)(m + (size_t)esrc[i] * 128 + lane * 2);
    a0 = max(a0, ra & 0xffffu); a1 = max(a1, ra >> 16);
  }
  *(u32*)(out + (size_t)n * 128 + lane * 2) = a0 | (a1 << 16);
}

__global__ __launch_bounds__(256) void agg256(const u16* __restrict__ m,
                                              const int* __restrict__ esrc,
                                              const int* __restrict__ off,
                                              u16* __restrict__ out) {
  int wv = threadIdx.x >> 6, lane = threadIdx.x & 63;
  int n = blockIdx.x * 4 + wv;
  if (n >= N_NODES) return;
  int s0 = off[n], s1 = off[n + 1];
  u32 a0 = 0, a1 = 0, a2 = 0, a3 = 0;
  int i = s0;
  for (; i + 1 < s1; i += 2) {
    int sa = esrc[i], sb = esrc[i + 1];
    uint2 ra = *(const uint2*)(m + (size_t)sa * 256 + lane * 4);
    uint2 rb = *(const uint2*)(m + (size_t)sb * 256 + lane * 4);
    a0 = max(a0, ra.x & 0xffffu); a1 = max(a1, ra.x >> 16);
    a2 = max(a2, ra.y & 0xffffu); a3 = max(a3, ra.y >> 16);
    a0 = max(a0, rb.x & 0xffffu); a1 = max(a1, rb.x >> 16);
    a2 = max(a2, rb.y & 0xffffu); a3 = max(a3, rb.y >> 16);
  }
  if (i < s1) {
    uint2 ra = *(const uint2*)(m + (size_t)esrc[i] * 256 + lane * 4);
    a0 = max(a0, ra.x & 0xffffu); a1 = max(a1, ra.x >> 16);
    a2 = max(a2, ra.y & 0xffffu); a3 = max(a3, ra.y >> 16);
  }
  uint2 w;
  w.x = a0 | (a1 << 16);
  w.y = a2 | (a3 << 16);
  *(uint2*)(out + (size_t)n * 256 + lane * 4) = w;
}

// ---------------- weight transpose: dst[n*ldo + ko + k] = src[k*Nn + n] ----------------
__global__ void transpose_k(const u16* __restrict__ src, u16* __restrict__ dstp,
                            int K, int nshift, int ldo, int ko) {
  int tid = blockIdx.x * 256 + threadIdx.x;
  int Nn = 1 << nshift;
  int k = tid >> nshift, n = tid & (Nn - 1);
  if (k >= K) return;
  dstp[(size_t)n * ldo + ko + k] = src[(size_t)k * Nn + n];
}

// ---------------- build permuted+padded ep_W1^T: [256 n][544 k'] ----------------
__global__ void build_wt1(const u16* __restrict__ w1, u16* __restrict__ dstp) {
  int n = blockIdx.x;  // 0..255
  for (int kp = threadIdx.x; kp < 544; kp += 256) {
    u16 v = 0;
    int ro = -1;
    if (kp < 256) ro = kp;                       // h1[src]
    else if (kp < 512) ro = 267 + (kp - 256);    // h1[dst]
    else if (kp < 517) ro = 256 + (kp - 512);    // sm[src]
    else if (kp < 522) ro = 523 + (kp - 517);    // sm[dst]
    else if (kp < 528) ro = 261 + (kp - 522);    // efeat
    if (ro >= 0) v = w1[(size_t)ro * 256 + n];
    dstp[(size_t)n * 544 + kp] = v;
  }
}

// ---------------- generic MFMA GEMM: C = relu(concat(A0,A1) @ Bt^T + bias) ----------------
__global__ __launch_bounds__(256) void gemm_mfma(
    const u16* __restrict__ A0, const u16* __restrict__ A1, int K0, int K1,
    const u16* __restrict__ Bt, const u16* __restrict__ bias,
    u16* __restrict__ C, float* __restrict__ Cf, const int* __restrict__ flag,
    int M, int Nld) {
  __shared__ __align__(16) u16 As[128 * 40];
  __shared__ __align__(16) u16 Bs[128 * 40];
  const int t = threadIdx.x;
  const int lane = t & 63, wv = t >> 6;
  const int wm = wv & 1, wn = wv >> 1;
  const int r = lane & 15, q = lane >> 4;
  const int bm = blockIdx.x, bn = blockIdx.y;
  const int Ktot = K0 + K1;
  const bool usef = (Cf != nullptr) && (*flag != 0);

  f32x4 acc[4][4];
#pragma unroll
  for (int i = 0; i < 4; i++)
#pragma unroll
    for (int j = 0; j < 4; j++) acc[i][j] = (f32x4){0.f, 0.f, 0.f, 0.f};

  for (int kc = 0; kc < Ktot; kc += 32) {
#pragma unroll
    for (int h = 0; h < 2; h++) {
      int idx = t + h * 256;          // 0..511
      int rr = idx >> 2, qq = idx & 3;
      int rowg = bm * 128 + rr;
      uint4 av = make_uint4(0, 0, 0, 0);
      if (rowg < M) {
        const u16* p = (kc < K0) ? (A0 + (size_t)rowg * K0 + kc)
                                 : (A1 + (size_t)rowg * K1 + (kc - K0));
        av = *(const uint4*)(p + qq * 8);
      }
      *(uint4*)&As[rr * 40 + qq * 8] = av;
      int ng = bn * 128 + rr;
      uint4 bv = *(const uint4*)(Bt + (size_t)ng * Ktot + kc + qq * 8);
      *(uint4*)&Bs[rr * 40 + qq * 8] = bv;
    }
    __syncthreads();
    bf16x8 af[4], bfm[4];
#pragma unroll
    for (int mi = 0; mi < 4; mi++)
      af[mi] = *(const bf16x8*)&As[(wm * 64 + mi * 16 + r) * 40 + q * 8];
#pragma unroll
    for (int ni = 0; ni < 4; ni++)
      bfm[ni] = *(const bf16x8*)&Bs[(wn * 64 + ni * 16 + r) * 40 + q * 8];
#pragma unroll
    for (int mi = 0; mi < 4; mi++)
#pragma unroll
      for (int ni = 0; ni < 4; ni++)
        acc[mi][ni] = __builtin_amdgcn_mfma_f32_16x16x32_bf16(af[mi], bfm[ni], acc[mi][ni], 0, 0, 0);
    __syncthreads();
  }

  float bv[4];
#pragma unroll
  for (int ni = 0; ni < 4; ni++) bv[ni] = b2f(bias[bn * 128 + wn * 64 + ni * 16 + r]);
#pragma unroll
  for (int mi = 0; mi < 4; mi++) {
#pragma unroll
    for (int i = 0; i < 4; i++) {
      int rowg = bm * 128 + wm * 64 + mi * 16 + q * 4 + i;
      if (rowg >= M) continue;
#pragma unroll
      for (int ni = 0; ni < 4; ni++) {
        int colg = bn * 128 + wn * 64 + ni * 16 + r;
        float v = acc[mi][ni][i] + bv[ni];
        v = v > 0.f ? v : 0.f;
        if (usef) Cf[(size_t)rowg * Nld + colg] = v;
        else C[(size_t)rowg * Nld + colg] = f2b(v);
      }
    }
  }
}

// ---------------- node head: node_pred = LN(h1@W + b), sm = softmax(node_pred) ----------------
__global__ __launch_bounds__(256) void node_head(
    const u16* __restrict__ h1, const u16* __restrict__ W, const u16* __restrict__ b,
    const u16* __restrict__ g, const u16* __restrict__ beta,
    u16* __restrict__ outN, float* __restrict__ outNf, const int* __restrict__ flag,
    u16* __restrict__ smOut) {
  __shared__ float Wl[256 * 5];
  __shared__ float bl[5], gl[5], betal[5];
  int t = threadIdx.x;
#pragma unroll
  for (int c = 0; c < 5; c++) Wl[t * 5 + c] = b2f(W[t * 5 + c]);
  if (t < 5) { bl[t] = b2f(b[t]); gl[t] = b2f(g[t]); betal[t] = b2f(beta[t]); }
  __syncthreads();
  int n = blockIdx.x * 256 + t;
  if (n >= N_NODES) return;
  const bool usef = (*flag != 0);
  float acc[5] = {0.f, 0.f, 0.f, 0.f, 0.f};
  const u16* hp = h1 + (size_t)n * 256;
  for (int k8 = 0; k8 < 32; k8++) {
    uint4 v = *(const uint4*)(hp + k8 * 8);
    u32 wds[4] = {v.x, v.y, v.z, v.w};
#pragma unroll
    for (int h = 0; h < 4; h++) {
      float x0 = b2f_lo(wds[h]), x1 = b2f_hi(wds[h]);
      int k = k8 * 8 + h * 2;
#pragma unroll
      for (int c = 0; c < 5; c++)
        acc[c] += x0 * Wl[k * 5 + c] + x1 * Wl[(k + 1) * 5 + c];
    }
  }
  float x[5], mu = 0.f;
#pragma unroll
  for (int c = 0; c < 5; c++) { x[c] = acc[c] + bl[c]; mu += x[c]; }
  mu *= 0.2f;
  float var = 0.f;
#pragma unroll
  for (int c = 0; c < 5; c++) { float d = x[c] - mu; var += d * d; }
  var *= 0.2f;
  float rstd = rsqrtf(fmaxf(var, 0.f) + 1e-5f);
  float v5[5], mx = -1e30f;
#pragma unroll
  for (int c = 0; c < 5; c++) {
    v5[c] = gl[c] * (x[c] - mu) * rstd + betal[c];
    if (usef) outNf[(size_t)n * 5 + c] = v5[c];
    else outN[(size_t)n * 5 + c] = f2b(v5[c]);
    mx = fmaxf(mx, v5[c]);
  }
  float s = 0.f, ex[5];
#pragma unroll
  for (int c = 0; c < 5; c++) { ex[c] = __expf(v5[c] - mx); s += ex[c]; }
  float inv = 1.f / s;
#pragma unroll
  for (int c = 0; c < 5; c++) smOut[(size_t)n * 5 + c] = f2b(ex[c] * inv);
}

// ---------------- fused edge MLP, 128-edge tile, 512 threads (8 waves: 2m x 4n) ----------------
// K-chunked staging: A (gathered rows) and B (wt1) tiled 32-wide in LDS.
__global__ __launch_bounds__(512, 4) void edge_mlp(
    const u16* __restrict__ h1, const u16* __restrict__ sm, const u16* __restrict__ ef,
    const int* __restrict__ src, const int* __restrict__ dst,
    const u16* __restrict__ wt1, const u16* __restrict__ b1,
    const u16* __restrict__ g, const u16* __restrict__ beta,
    const u16* __restrict__ w2, const u16* __restrict__ b2,
    u16* __restrict__ outE, float* __restrict__ outEf, const int* __restrict__ flag) {
  __shared__ __align__(16) u16 As[128 * 40];   // 128 edges x 32k (+8 pad)
  __shared__ __align__(16) u16 Bs[256 * 40];   // 256 cols  x 32k (+8 pad)
  __shared__ int sidx[128], didx[128];
  __shared__ float red[4][128][2];
  __shared__ float mr[128][2];
  const int t = threadIdx.x;
  const int eb = blockIdx.x * 128;
  if (t < 128) sidx[t] = src[eb + t];
  else if (t < 256) didx[t - 128] = dst[eb + t - 128];
  __syncthreads();

  const int lane = t & 63, wv = t >> 6;
  const int wm = wv >> 2, wn = wv & 3;
  const int r = lane & 15, q = lane >> 4;
  const int rr = t >> 2, qq = t & 3;   // A staging: row rr, 8-col chunk qq

  f32x4 acc[4][4];
#pragma unroll
  for (int mi = 0; mi < 4; mi++)
#pragma unroll
    for (int ni = 0; ni < 4; ni++) acc[mi][ni] = (f32x4){0.f, 0.f, 0.f, 0.f};

  for (int kc = 0; kc < 544; kc += 32) {
    // --- stage A tile (gather) ---
    int c0 = kc + qq * 8;
    if (kc < 512) {
      const u16* p = (c0 < 256) ? (h1 + (size_t)sidx[rr] * 256 + c0)
                                : (h1 + (size_t)didx[rr] * 256 + (c0 - 256));
      *(uint4*)&As[rr * 40 + qq * 8] = *(const uint4*)p;
    } else {
      // tail chunk: [sm_s(5) | sm_d(5) | ef(6) | pad(16)]
      u16 tv[8];
#pragma unroll
      for (int jj = 0; jj < 8; jj++) {
        int j = qq * 8 + jj;  // 0..31
        u16 val = 0;
        if (j < 5) val = sm[(size_t)sidx[rr] * 5 + j];
        else if (j < 10) val = sm[(size_t)didx[rr] * 5 + (j - 5)];
        else if (j < 16) val = ef[(size_t)(eb + rr) * 6 + (j - 10)];
        tv[jj] = val;
      }
      *(uint4*)&As[rr * 40 + qq * 8] = *(const uint4*)tv;
    }
    // --- stage B tile ---
#pragma unroll
    for (int h = 0; h < 2; h++) {
      int idx = t + h * 512;      // 0..1023
      int cc = idx >> 2, q2 = idx & 3;
      *(uint4*)&Bs[cc * 40 + q2 * 8] =
          *(const uint4*)(wt1 + (size_t)cc * 544 + kc + q2 * 8);
    }
    __syncthreads();
    bf16x8 af[4], bfr[4];
#pragma unroll
    for (int mi = 0; mi < 4; mi++)
      af[mi] = *(const bf16x8*)&As[(wm * 64 + mi * 16 + r) * 40 + q * 8];
#pragma unroll
    for (int ni = 0; ni < 4; ni++)
      bfr[ni] = *(const bf16x8*)&Bs[(wn * 64 + ni * 16 + r) * 40 + q * 8];
#pragma unroll
    for (int mi = 0; mi < 4; mi++)
#pragma unroll
      for (int ni = 0; ni < 4; ni++)
        acc[mi][ni] = __builtin_amdgcn_mfma_f32_16x16x32_bf16(af[mi], bfr[ni], acc[mi][ni], 0, 0, 0);
    __syncthreads();
  }

  float b1v[4], gv[4], bev[4], w20[4], w21[4];
#pragma unroll
  for (int ni = 0; ni < 4; ni++) {
    int c = wn * 64 + ni * 16 + r;
    b1v[ni] = b2f(b1[c]); gv[ni] = b2f(g[c]); bev[ni] = b2f(beta[c]);
    w20[ni] = b2f(w2[c * 2]); w21[ni] = b2f(w2[c * 2 + 1]);
  }
  // pass 1: LN stats — each wave covers 64 cols of rows wm*64..wm*64+63
#pragma unroll
  for (int mi = 0; mi < 4; mi++)
#pragma unroll
    for (int i = 0; i < 4; i++) {
      float ps = 0.f, pq = 0.f;
#pragma unroll
      for (int ni = 0; ni < 4; ni++) {
        float x = acc[mi][ni][i] + b1v[ni];
        ps += x; pq += x * x;
      }
      for (int msk = 1; msk < 16; msk <<= 1) {
        ps += __shfl_xor(ps, msk, 64);
        pq += __shfl_xor(pq, msk, 64);
      }
      if (r == 0) {
        int row = wm * 64 + mi * 16 + q * 4 + i;
        red[wn][row][0] = ps; red[wn][row][1] = pq;
      }
    }
  __syncthreads();
  if (t < 128) {
    float s = red[0][t][0] + red[1][t][0] + red[2][t][0] + red[3][t][0];
    float sq = red[0][t][1] + red[1][t][1] + red[2][t][1] + red[3][t][1];
    float mean = s * (1.f / 256.f);
    float var = sq * (1.f / 256.f) - mean * mean;
    mr[t][0] = mean; mr[t][1] = rsqrtf(fmaxf(var, 0.f) + 1e-5f);
  }
  __syncthreads();
  // pass 2: normalize + relu + W2 partials
#pragma unroll
  for (int mi = 0; mi < 4; mi++)
#pragma unroll
    for (int i = 0; i < 4; i++) {
      int row = wm * 64 + mi * 16 + q * 4 + i;
      float mean = mr[row][0], rstd = mr[row][1];
      float p0 = 0.f, p1 = 0.f;
#pragma unroll
      for (int ni = 0; ni < 4; ni++) {
        float x = acc[mi][ni][i] + b1v[ni];
        float y = (x - mean) * rstd * gv[ni] + bev[ni];
        y = fmaxf(y, 0.f);
        p0 += y * w20[ni]; p1 += y * w21[ni];
      }
      for (int msk = 1; msk < 16; msk <<= 1) {
        p0 += __shfl_xor(p0, msk, 64);
        p1 += __shfl_xor(p1, msk, 64);
      }
      if (r == 0) { red[wn][row][0] = p0; red[wn][row][1] = p1; }
    }
  __syncthreads();
  if (t < 256) {
    int row = t >> 1, c = t & 1;
    float v = red[0][row][c] + red[1][row][c] + red[2][row][c] + red[3][row][c] + b2f(b2[c]);
    if (*flag) outEf[(size_t)(eb + row) * 2 + c] = v;
    else outE[(size_t)(eb + row) * 2 + c] = f2b(v);
  }
}

extern "C" void kernel_launch(void* const* d_in, const int* in_sizes, int n_in,
                              void* d_out, int out_size, void* d_ws, size_t ws_size,
                              hipStream_t stream) {
  char* wp = (char*)d_ws;
  auto alloc = [&](size_t bytes) -> char* {
    char* p = wp; wp += (bytes + 255) & ~(size_t)255; return p;
  };
  int* flag       = (int*)alloc(256);
  // canonical bf16 copies of all float inputs
  u16* c_h        = (u16*)alloc((size_t)N_NODES * 128 * 2);
  u16* c_ef       = (u16*)alloc((size_t)N_EDGES * 6 * 2);
  static const int pidx[20] = {4,5,6,7,8, 9,10,11,12, 13,14,15,16,17,18, 19,20,21,22,23};
  static const int pn[20]   = {16384,128,32768,256,32768, 1280,5,5,5,
                               135168,256,256,256,512,2, 65536,256,32768,128,32768};
  u16* cp[20];
  for (int a = 0; a < 20; a++) cp[a] = (u16*)alloc((size_t)pn[a] * 2);

  u16* wt_encpool = (u16*)alloc(128 * 128 * 2);
  u16* wt_enc     = (u16*)alloc(256 * 256 * 2);
  u16* wt_decpool = (u16*)alloc(256 * 256 * 2);
  u16* wt_dec     = (u16*)alloc(128 * 512 * 2);
  u16* wt_ep1     = (u16*)alloc(256 * 544 * 2);
  u16* m_buf      = (u16*)alloc((size_t)N_NODES * 256 * 2);
  u16* aggb       = (u16*)alloc((size_t)N_NODES * 256 * 2);
  u16* h1b        = (u16*)alloc((size_t)N_NODES * 256 * 2);
  u16* smb        = (u16*)alloc((size_t)N_NODES * 5 * 2);
  // CSR
  int* deg        = (int*)alloc((size_t)N_NODES * 4);
  int* off        = (int*)alloc((size_t)(N_NODES + 1) * 4);
  int* cursor     = (int*)alloc((size_t)N_NODES * 4);
  int* esrc       = (int*)alloc((size_t)N_EDGES * 4);

  const int* src = (const int*)d_in[2];
  const int* dst = (const int*)d_in[3];

  u16* outN = (u16*)d_out;
  u16* outE = outN + (size_t)N_NODES * 5;
  u16* outH = outN + 1110000;
  float* outNf = (float*)d_out;
  float* outEf = outNf + (size_t)N_NODES * 5;
  float* outHf = outNf + 1110000;

  // --- dtype sniff + input conversion ---
  sniff<<<1, 256, 0, stream>>>((const u16*)d_in[0], flag);
  conv_arr<<<15000, 256, 0, stream>>>(d_in[0], c_h, N_NODES * 128, flag);
  conv_arr<<<11250, 256, 0, stream>>>(d_in[1], c_ef, N_EDGES * 6, flag);
  ConvTab tab;
  int off_a = 0;
  for (int a = 0; a < 20; a++) {
    tab.e[a].s = d_in[pidx[a]]; tab.e[a].d = cp[a]; tab.e[a].n = pn[a]; tab.e[a].off = off_a;
    off_a += pn[a];
  }
  tab.total = off_a;
  conv_params<<<(off_a + 255) / 256, 256, 0, stream>>>(tab, flag);

  const u16 *enc_Wpool = cp[0], *enc_bpool = cp[1], *enc_Wself = cp[2], *enc_bself = cp[3],
            *enc_Wneigh = cp[4], *np_W = cp[5], *np_b = cp[6], *np_g = cp[7], *np_beta = cp[8],
            *ep_W1 = cp[9], *ep_b1 = cp[10], *ep_g = cp[11], *ep_beta = cp[12],
            *ep_W2 = cp[13], *ep_b2 = cp[14], *dec_Wpool = cp[15], *dec_bpool = cp[16],
            *dec_Wself = cp[17], *dec_bself = cp[18], *dec_Wneigh = cp[19];

  // --- CSR build (shared by both aggregations) ---
  hipMemsetAsync(deg, 0, (size_t)N_NODES * 4, stream);
  deg_count<<<1875, 256, 0, stream>>>(dst, deg, N_EDGES);
  scan_off<<<1, 256, 0, stream>>>(deg, off, N_NODES);
  hipMemcpyAsync(cursor, off, (size_t)N_NODES * 4, hipMemcpyDeviceToDevice, stream);
  fill_csr<<<1875, 256, 0, stream>>>(src, dst, cursor, esrc, N_EDGES);

  // --- weight prep ---
  transpose_k<<<64, 256, 0, stream>>>(enc_Wpool, wt_encpool, 128, 7, 128, 0);
  transpose_k<<<128, 256, 0, stream>>>(enc_Wself, wt_enc, 128, 8, 256, 0);
  transpose_k<<<128, 256, 0, stream>>>(enc_Wneigh, wt_enc, 128, 8, 256, 128);
  transpose_k<<<256, 256, 0, stream>>>(dec_Wpool, wt_decpool, 256, 8, 256, 0);
  transpose_k<<<128, 256, 0, stream>>>(dec_Wself, wt_dec, 256, 7, 512, 0);
  transpose_k<<<128, 256, 0, stream>>>(dec_Wneigh, wt_dec, 256, 7, 512, 256);
  build_wt1<<<256, 256, 0, stream>>>(ep_W1, wt_ep1);

  // --- encoder ---
  gemm_mfma<<<dim3(235, 1), 256, 0, stream>>>(c_h, nullptr, 128, 0, wt_encpool,
                                              enc_bpool, m_buf, nullptr, flag, N_NODES, 128);
  agg128<<<7500, 256, 0, stream>>>(m_buf, esrc, off, aggb);
  gemm_mfma<<<dim3(235, 2), 256, 0, stream>>>(c_h, aggb, 128, 128, wt_enc,
                                              enc_bself, h1b, nullptr, flag, N_NODES, 256);
  // --- node head ---
  node_head<<<118, 256, 0, stream>>>(h1b, np_W, np_b, np_g, np_beta, outN, outNf, flag, smb);
  // --- edge head ---
  edge_mlp<<<N_EDGES / 128, 512, 0, stream>>>(h1b, smb, c_ef, src, dst, wt_ep1,
                                              ep_b1, ep_g, ep_beta, ep_W2, ep_b2,
                                              outE, outEf, flag);
  // --- decoder ---
  gemm_mfma<<<dim3(235, 2), 256, 0, stream>>>(h1b, nullptr, 256, 0, wt_decpool,
                                              dec_bpool, m_buf, nullptr, flag, N_NODES, 256);
  agg256<<<7500, 256, 0, stream>>>(m_buf, esrc, off, aggb);
  gemm_mfma<<<dim3(235, 1), 256, 0, stream>>>(h1b, aggb, 256, 256, wt_dec,
                                              dec_bself, outH, outHf, flag, N_NODES, 128);
}

// Round 5
// 683.930 us; speedup vs baseline: 2.0875x; 1.0427x over previous
//
#include <hip/hip_runtime.h>

typedef unsigned short u16;
typedef unsigned int u32;
typedef __bf16 bf16_t;
typedef bf16_t bf16x8 __attribute__((ext_vector_type(8)));
typedef float f32x4 __attribute__((ext_vector_type(4)));

#define N_NODES 30000
#define N_EDGES 480000

static __device__ __forceinline__ float b2f(u16 u) {
  return __uint_as_float(((u32)u) << 16);
}
static __device__ __forceinline__ float b2f_lo(u32 w) {
  return __uint_as_float(w << 16);
}
static __device__ __forceinline__ float b2f_hi(u32 w) {
  return __uint_as_float(w & 0xffff0000u);
}
static __device__ __forceinline__ u16 f2b(float f) {
  u32 x = __float_as_uint(f);
  u32 r = (x + 0x7fffu + ((x >> 16) & 1u)) >> 16;
  return (u16)r;
}

// ---------------- dtype sniff: bf16 storage (flag=0) vs f32 storage (flag=1) ----------------
__global__ void sniff(const u16* __restrict__ h, int* __restrict__ flag) {
  int t = threadIdx.x;
  int bad = 0;
#pragma unroll
  for (int i = 0; i < 4; i++) {
    u32 e = ((u32)h[t * 4 + i] >> 7) & 0xFFu;
    if (e >= 0x8Eu) bad = 1;  // impossible magnitude for N(0,1) bf16 data
  }
  int r = __syncthreads_or(bad);
  if (t == 0) *flag = r ? 1 : 0;
}

// ---------------- convert one big array to canonical bf16 ----------------
__global__ __launch_bounds__(256) void conv_arr(const void* __restrict__ src,
                                                u16* __restrict__ dst, int n,
                                                const int* __restrict__ flag) {
  int i = blockIdx.x * 256 + threadIdx.x;
  if (i >= n) return;
  if (*flag) dst[i] = f2b(((const float*)src)[i]);
  else dst[i] = ((const u16*)src)[i];
}

struct ConvDesc { const void* s; u16* d; int n; int off; };
struct ConvTab { ConvDesc e[20]; int total; };

__global__ __launch_bounds__(256) void conv_params(ConvTab tab, const int* __restrict__ flag) {
  int i = blockIdx.x * 256 + threadIdx.x;
  if (i >= tab.total) return;
  int f = *flag;
#pragma unroll 1
  for (int a = 0; a < 20; a++) {
    int j = i - tab.e[a].off;
    if (j >= 0 && j < tab.e[a].n) {
      if (f) tab.e[a].d[j] = f2b(((const float*)tab.e[a].s)[j]);
      else tab.e[a].d[j] = ((const u16*)tab.e[a].s)[j];
      return;
    }
  }
}

// ---------------- CSR build: deg -> off (scan) -> fill ----------------
__global__ __launch_bounds__(256) void deg_count(const int* __restrict__ dst,
                                                 int* __restrict__ deg, int nE) {
  int e = blockIdx.x * 256 + threadIdx.x;
  if (e < nE) atomicAdd(&deg[dst[e]], 1);
}

__global__ __launch_bounds__(256) void scan_off(const int* __restrict__ deg,
                                                int* __restrict__ off, int n) {
  __shared__ int carry;
  __shared__ int wsum[4];
  int t = threadIdx.x, lane = t & 63, wv = t >> 6;
  if (t == 0) { carry = 0; off[0] = 0; }
  __syncthreads();
  for (int base = 0; base < n; base += 256) {
    int v = (base + t < n) ? deg[base + t] : 0;
    int x = v;
#pragma unroll
    for (int d = 1; d < 64; d <<= 1) {
      int y = __shfl_up(x, d, 64);
      if (lane >= d) x += y;
    }
    if (lane == 63) wsum[wv] = x;
    __syncthreads();
    int wadd = 0;
    for (int w = 0; w < wv; w++) wadd += wsum[w];
    int incl = x + wadd + carry;
    if (base + t < n) off[base + t + 1] = incl;
    __syncthreads();
    if (t == 255) carry = incl;
    __syncthreads();
  }
}

__global__ __launch_bounds__(256) void fill_csr(const int* __restrict__ src,
                                                const int* __restrict__ dst,
                                                int* __restrict__ cursor,
                                                int* __restrict__ esrc, int nE) {
  int e = blockIdx.x * 256 + threadIdx.x;
  if (e >= nE) return;
  int p = atomicAdd(&cursor[dst[e]], 1);
  esrc[p] = src[e];
}

// ---------------- CSR max-aggregate: out[n] = max over in-edges of m[src] (bf16, >=0) ----------------
// Unsigned compare on raw u16 == float compare for non-negative bf16.
__global__ __launch_bounds__(256) void agg128(const u16* __restrict__ m,
                                              const int* __restrict__ esrc,
                                              const int* __restrict__ off,
                                              u16* __restrict__ out) {
  int wv = threadIdx.x >> 6, lane = threadIdx.x & 63;
  int n = blockIdx.x * 4 + wv;
  if (n >= N_NODES) return;
  int s0 = off[n], s1 = off[n + 1];
  u32 a0 = 0, a1 = 0;
  int i = s0;
  for (; i + 1 < s1; i += 2) {
    int sa = esrc[i], sb = esrc[i + 1];
    u32 ra = *(const u32*)(m + (size_t)sa * 128 + lane * 2);
    u32 rb = *(const u32*)(m + (size_t)sb * 128 + lane * 2);
    a0 = max(a0, ra & 0xffffu); a1 = max(a1, ra >> 16);
    a0 = max(a0, rb & 0xffffu); a1 = max(a1, rb >> 16);
  }
  if (i < s1) {
    u32 ra = *(const u32*)(m + (size_t)esrc[i] * 128 + lane * 2);
    a0 = max(a0, ra & 0xffffu); a1 = max(a1, ra >> 16);
  }
  *(u32*)(out + (size_t)n * 128 + lane * 2) = a0 | (a1 << 16);
}

__global__ __launch_bounds__(256) void agg256(const u16* __restrict__ m,
                                              const int* __restrict__ esrc,
                                              const int* __restrict__ off,
                                              u16* __restrict__ out) {
  int wv = threadIdx.x >> 6, lane = threadIdx.x & 63;
  int n = blockIdx.x * 4 + wv;
  if (n >= N_NODES) return;
  int s0 = off[n], s1 = off[n + 1];
  u32 a0 = 0, a1 = 0, a2 = 0, a3 = 0;
  int i = s0;
  for (; i + 1 < s1; i += 2) {
    int sa = esrc[i], sb = esrc[i + 1];
    uint2 ra = *(const uint2*)(m + (size_t)sa * 256 + lane * 4);
    uint2 rb = *(const uint2*)(m + (size_t)sb * 256 + lane * 4);
    a0 = max(a0, ra.x & 0xffffu); a1 = max(a1, ra.x >> 16);
    a2 = max(a2, ra.y & 0xffffu); a3 = max(a3, ra.y >> 16);
    a0 = max(a0, rb.x & 0xffffu); a1 = max(a1, rb.x >> 16);
    a2 = max(a2, rb.y & 0xffffu); a3 = max(a3, rb.y >> 16);
  }
  if (i < s1) {
    uint2 ra = *(const uint2*)(m + (size_t)esrc[i] * 256 + lane * 4);
    a0 = max(a0, ra.x & 0xffffu); a1 = max(a1, ra.x >> 16);
    a2 = max(a2, ra.y & 0xffffu); a3 = max(a3, ra.y >> 16);
  }
  uint2 w;
  w.x = a0 | (a1 << 16);
  w.y = a2 | (a3 << 16);
  *(uint2*)(out + (size_t)n * 256 + lane * 4) = w;
}

// ---------------- weight transpose: dst[n*ldo + ko + k] = src[k*Nn + n] ----------------
__global__ void transpose_k(const u16* __restrict__ src, u16* __restrict__ dstp,
                            int K, int nshift, int ldo, int ko) {
  int tid = blockIdx.x * 256 + threadIdx.x;
  int Nn = 1 << nshift;
  int k = tid >> nshift, n = tid & (Nn - 1);
  if (k >= K) return;
  dstp[(size_t)n * ldo + ko + k] = src[(size_t)k * Nn + n];
}

// ---------------- generic MFMA GEMM: C = act(concat(A0,A1) @ Bt^T + bias) ----------------
__global__ __launch_bounds__(256) void gemm_mfma(
    const u16* __restrict__ A0, const u16* __restrict__ A1, int K0, int K1,
    const u16* __restrict__ Bt, const u16* __restrict__ bias, int do_relu,
    u16* __restrict__ C, float* __restrict__ Cf, const int* __restrict__ flag,
    int M, int Nld) {
  __shared__ __align__(16) u16 As[128 * 40];
  __shared__ __align__(16) u16 Bs[128 * 40];
  const int t = threadIdx.x;
  const int lane = t & 63, wv = t >> 6;
  const int wm = wv & 1, wn = wv >> 1;
  const int r = lane & 15, q = lane >> 4;
  const int bm = blockIdx.x, bn = blockIdx.y;
  const int Ktot = K0 + K1;
  const bool usef = (Cf != nullptr) && (*flag != 0);

  f32x4 acc[4][4];
#pragma unroll
  for (int i = 0; i < 4; i++)
#pragma unroll
    for (int j = 0; j < 4; j++) acc[i][j] = (f32x4){0.f, 0.f, 0.f, 0.f};

  for (int kc = 0; kc < Ktot; kc += 32) {
#pragma unroll
    for (int h = 0; h < 2; h++) {
      int idx = t + h * 256;          // 0..511
      int rr = idx >> 2, qq = idx & 3;
      int rowg = bm * 128 + rr;
      uint4 av = make_uint4(0, 0, 0, 0);
      if (rowg < M) {
        const u16* p = (kc < K0) ? (A0 + (size_t)rowg * K0 + kc)
                                 : (A1 + (size_t)rowg * K1 + (kc - K0));
        av = *(const uint4*)(p + qq * 8);
      }
      *(uint4*)&As[rr * 40 + qq * 8] = av;
      int ng = bn * 128 + rr;
      uint4 bv = *(const uint4*)(Bt + (size_t)ng * Ktot + kc + qq * 8);
      *(uint4*)&Bs[rr * 40 + qq * 8] = bv;
    }
    __syncthreads();
    bf16x8 af[4], bfm[4];
#pragma unroll
    for (int mi = 0; mi < 4; mi++)
      af[mi] = *(const bf16x8*)&As[(wm * 64 + mi * 16 + r) * 40 + q * 8];
#pragma unroll
    for (int ni = 0; ni < 4; ni++)
      bfm[ni] = *(const bf16x8*)&Bs[(wn * 64 + ni * 16 + r) * 40 + q * 8];
#pragma unroll
    for (int mi = 0; mi < 4; mi++)
#pragma unroll
      for (int ni = 0; ni < 4; ni++)
        acc[mi][ni] = __builtin_amdgcn_mfma_f32_16x16x32_bf16(af[mi], bfm[ni], acc[mi][ni], 0, 0, 0);
    __syncthreads();
  }

  float bv[4];
#pragma unroll
  for (int ni = 0; ni < 4; ni++)
    bv[ni] = bias ? b2f(bias[bn * 128 + wn * 64 + ni * 16 + r]) : 0.f;
#pragma unroll
  for (int mi = 0; mi < 4; mi++) {
#pragma unroll
    for (int i = 0; i < 4; i++) {
      int rowg = bm * 128 + wm * 64 + mi * 16 + q * 4 + i;
      if (rowg >= M) continue;
#pragma unroll
      for (int ni = 0; ni < 4; ni++) {
        int colg = bn * 128 + wn * 64 + ni * 16 + r;
        float v = acc[mi][ni][i] + bv[ni];
        if (do_relu) v = v > 0.f ? v : 0.f;
        if (usef) Cf[(size_t)rowg * Nld + colg] = v;
        else C[(size_t)rowg * Nld + colg] = f2b(v);
      }
    }
  }
}

// ---------------- node head: node_pred = LN(h1@W + b), smb32 = [softmax | 0-pad] ----------------
__global__ __launch_bounds__(256) void node_head(
    const u16* __restrict__ h1, const u16* __restrict__ W, const u16* __restrict__ b,
    const u16* __restrict__ g, const u16* __restrict__ beta,
    u16* __restrict__ outN, float* __restrict__ outNf, const int* __restrict__ flag,
    u16* __restrict__ smOut) {
  __shared__ float Wl[256 * 5];
  __shared__ float bl[5], gl[5], betal[5];
  int t = threadIdx.x;
#pragma unroll
  for (int c = 0; c < 5; c++) Wl[t * 5 + c] = b2f(W[t * 5 + c]);
  if (t < 5) { bl[t] = b2f(b[t]); gl[t] = b2f(g[t]); betal[t] = b2f(beta[t]); }
  __syncthreads();
  int n = blockIdx.x * 256 + t;
  if (n >= N_NODES) return;
  const bool usef = (*flag != 0);
  float acc[5] = {0.f, 0.f, 0.f, 0.f, 0.f};
  const u16* hp = h1 + (size_t)n * 256;
  for (int k8 = 0; k8 < 32; k8++) {
    uint4 v = *(const uint4*)(hp + k8 * 8);
    u32 wds[4] = {v.x, v.y, v.z, v.w};
#pragma unroll
    for (int h = 0; h < 4; h++) {
      float x0 = b2f_lo(wds[h]), x1 = b2f_hi(wds[h]);
      int k = k8 * 8 + h * 2;
#pragma unroll
      for (int c = 0; c < 5; c++)
        acc[c] += x0 * Wl[k * 5 + c] + x1 * Wl[(k + 1) * 5 + c];
    }
  }
  float x[5], mu = 0.f;
#pragma unroll
  for (int c = 0; c < 5; c++) { x[c] = acc[c] + bl[c]; mu += x[c]; }
  mu *= 0.2f;
  float var = 0.f;
#pragma unroll
  for (int c = 0; c < 5; c++) { float d = x[c] - mu; var += d * d; }
  var *= 0.2f;
  float rstd = rsqrtf(fmaxf(var, 0.f) + 1e-5f);
  float v5[5], mx = -1e30f;
#pragma unroll
  for (int c = 0; c < 5; c++) {
    v5[c] = gl[c] * (x[c] - mu) * rstd + betal[c];
    if (usef) outNf[(size_t)n * 5 + c] = v5[c];
    else outN[(size_t)n * 5 + c] = f2b(v5[c]);
    mx = fmaxf(mx, v5[c]);
  }
  float s = 0.f, ex[5];
#pragma unroll
  for (int c = 0; c < 5; c++) { ex[c] = __expf(v5[c] - mx); s += ex[c]; }
  float inv = 1.f / s;
  u16 row[32];
#pragma unroll
  for (int c = 0; c < 5; c++) row[c] = f2b(ex[c] * inv);
#pragma unroll
  for (int c = 5; c < 32; c++) row[c] = 0;
#pragma unroll
  for (int c = 0; c < 4; c++)
    *(uint4*)(smOut + (size_t)n * 32 + c * 8) = *(const uint4*)&row[c * 8];
}

// ---------------- edge pointwise: y = U[src]+V[dst]+ef@Wef -> LN -> relu -> @W2+b2 ----------------
// One wave per edge; lane l owns cols 4l..4l+3. No LDS, no MFMA, no syncthreads.
__global__ __launch_bounds__(256) void edge_pt(
    const u16* __restrict__ U, const u16* __restrict__ V, const u16* __restrict__ ef,
    const int* __restrict__ src, const int* __restrict__ dst,
    const u16* __restrict__ w1raw,
    const u16* __restrict__ g, const u16* __restrict__ beta,
    const u16* __restrict__ w2, const u16* __restrict__ b2,
    u16* __restrict__ outE, float* __restrict__ outEf, const int* __restrict__ flag) {
  const int t = threadIdx.x;
  const int lane = t & 63, wv = t >> 6;
  const int c0 = lane * 4;
  // per-lane constants in registers
  float wef[6][4], gl[4], bl[4], w20[4], w21[4];
#pragma unroll
  for (int k = 0; k < 6; k++) {
    u32 wa = *(const u32*)(w1raw + (size_t)(261 + k) * 256 + c0);
    u32 wb = *(const u32*)(w1raw + (size_t)(261 + k) * 256 + c0 + 2);
    wef[k][0] = b2f_lo(wa); wef[k][1] = b2f_hi(wa);
    wef[k][2] = b2f_lo(wb); wef[k][3] = b2f_hi(wb);
  }
#pragma unroll
  for (int j = 0; j < 4; j++) {
    gl[j] = b2f(g[c0 + j]); bl[j] = b2f(beta[c0 + j]);
    w20[j] = b2f(w2[(c0 + j) * 2]); w21[j] = b2f(w2[(c0 + j) * 2 + 1]);
  }
  const float b20 = b2f(b2[0]), b21 = b2f(b2[1]);
  const bool usef = (*flag != 0);
  const int stride = gridDim.x * 4;
  for (int e = blockIdx.x * 4 + wv; e < N_EDGES; e += stride) {
    int s = src[e], d = dst[e];
    uint2 uu = *(const uint2*)(U + (size_t)s * 256 + c0);
    uint2 vx = *(const uint2*)(V + (size_t)d * 256 + c0);
    u32 e0 = *(const u32*)(ef + (size_t)e * 6);
    u32 e1 = *(const u32*)(ef + (size_t)e * 6 + 2);
    u32 e2 = *(const u32*)(ef + (size_t)e * 6 + 4);
    float xe[6] = {b2f_lo(e0), b2f_hi(e0), b2f_lo(e1), b2f_hi(e1), b2f_lo(e2), b2f_hi(e2)};
    float y[4];
    y[0] = b2f_lo(uu.x) + b2f_lo(vx.x);
    y[1] = b2f_hi(uu.x) + b2f_hi(vx.x);
    y[2] = b2f_lo(uu.y) + b2f_lo(vx.y);
    y[3] = b2f_hi(uu.y) + b2f_hi(vx.y);
#pragma unroll
    for (int k = 0; k < 6; k++)
#pragma unroll
      for (int j = 0; j < 4; j++) y[j] += xe[k] * wef[k][j];
    float ps = y[0] + y[1] + y[2] + y[3];
    float pq = y[0] * y[0] + y[1] * y[1] + y[2] * y[2] + y[3] * y[3];
#pragma unroll
    for (int m = 1; m < 64; m <<= 1) {
      ps += __shfl_xor(ps, m, 64);
      pq += __shfl_xor(pq, m, 64);
    }
    float mean = ps * (1.f / 256.f);
    float var = pq * (1.f / 256.f) - mean * mean;
    float rstd = rsqrtf(fmaxf(var, 0.f) + 1e-5f);
    float p0 = 0.f, p1 = 0.f;
#pragma unroll
    for (int j = 0; j < 4; j++) {
      float yy = (y[j] - mean) * rstd * gl[j] + bl[j];
      yy = fmaxf(yy, 0.f);
      p0 += yy * w20[j]; p1 += yy * w21[j];
    }
#pragma unroll
    for (int m = 1; m < 64; m <<= 1) {
      p0 += __shfl_xor(p0, m, 64);
      p1 += __shfl_xor(p1, m, 64);
    }
    if (lane == 0) {
      float v0 = p0 + b20, v1 = p1 + b21;
      if (usef) {
        *(float2*)(outEf + (size_t)e * 2) = make_float2(v0, v1);
      } else {
        u32 pk = (u32)f2b(v0) | ((u32)f2b(v1) << 16);
        *(u32*)(outE + (size_t)e * 2) = pk;
      }
    }
  }
}

extern "C" void kernel_launch(void* const* d_in, const int* in_sizes, int n_in,
                              void* d_out, int out_size, void* d_ws, size_t ws_size,
                              hipStream_t stream) {
  char* wp = (char*)d_ws;
  auto alloc = [&](size_t bytes) -> char* {
    char* p = wp; wp += (bytes + 255) & ~(size_t)255; return p;
  };
  int* flag       = (int*)alloc(256);
  // canonical bf16 copies of all float inputs
  u16* c_h        = (u16*)alloc((size_t)N_NODES * 128 * 2);
  u16* c_ef       = (u16*)alloc((size_t)N_EDGES * 6 * 2);
  static const int pidx[20] = {4,5,6,7,8, 9,10,11,12, 13,14,15,16,17,18, 19,20,21,22,23};
  static const int pn[20]   = {16384,128,32768,256,32768, 1280,5,5,5,
                               135168,256,256,256,512,2, 65536,256,32768,128,32768};
  u16* cp[20];
  for (int a = 0; a < 20; a++) cp[a] = (u16*)alloc((size_t)pn[a] * 2);

  u16* wt_encpool = (u16*)alloc(128 * 128 * 2);
  u16* wt_enc     = (u16*)alloc(256 * 256 * 2);
  u16* wt_decpool = (u16*)alloc(256 * 256 * 2);
  u16* wt_dec     = (u16*)alloc(128 * 512 * 2);
  u16* wt_U       = (u16*)alloc(256 * 288 * 2);
  u16* wt_V       = (u16*)alloc(256 * 288 * 2);
  u16* m_buf      = (u16*)alloc((size_t)N_NODES * 256 * 2);  // also U (edge phase)
  u16* aggb       = (u16*)alloc((size_t)N_NODES * 256 * 2);  // also V (edge phase)
  u16* h1b        = (u16*)alloc((size_t)N_NODES * 256 * 2);
  u16* smb32      = (u16*)alloc((size_t)N_NODES * 32 * 2);
  // CSR
  int* deg        = (int*)alloc((size_t)N_NODES * 4);
  int* off        = (int*)alloc((size_t)(N_NODES + 1) * 4);
  int* cursor     = (int*)alloc((size_t)N_NODES * 4);
  int* esrc       = (int*)alloc((size_t)N_EDGES * 4);

  const int* src = (const int*)d_in[2];
  const int* dst = (const int*)d_in[3];

  u16* outN = (u16*)d_out;
  u16* outE = outN + (size_t)N_NODES * 5;
  u16* outH = outN + 1110000;
  float* outNf = (float*)d_out;
  float* outEf = outNf + (size_t)N_NODES * 5;
  float* outHf = outNf + 1110000;

  // --- dtype sniff + input conversion ---
  sniff<<<1, 256, 0, stream>>>((const u16*)d_in[0], flag);
  conv_arr<<<15000, 256, 0, stream>>>(d_in[0], c_h, N_NODES * 128, flag);
  conv_arr<<<11250, 256, 0, stream>>>(d_in[1], c_ef, N_EDGES * 6, flag);
  ConvTab tab;
  int off_a = 0;
  for (int a = 0; a < 20; a++) {
    tab.e[a].s = d_in[pidx[a]]; tab.e[a].d = cp[a]; tab.e[a].n = pn[a]; tab.e[a].off = off_a;
    off_a += pn[a];
  }
  tab.total = off_a;
  conv_params<<<(off_a + 255) / 256, 256, 0, stream>>>(tab, flag);

  const u16 *enc_Wpool = cp[0], *enc_bpool = cp[1], *enc_Wself = cp[2], *enc_bself = cp[3],
            *enc_Wneigh = cp[4], *np_W = cp[5], *np_b = cp[6], *np_g = cp[7], *np_beta = cp[8],
            *ep_W1 = cp[9], *ep_b1 = cp[10], *ep_g = cp[11], *ep_beta = cp[12],
            *ep_W2 = cp[13], *ep_b2 = cp[14], *dec_Wpool = cp[15], *dec_bpool = cp[16],
            *dec_Wself = cp[17], *dec_bself = cp[18], *dec_Wneigh = cp[19];

  // --- CSR build (shared by both aggregations) ---
  hipMemsetAsync(deg, 0, (size_t)N_NODES * 4, stream);
  deg_count<<<1875, 256, 0, stream>>>(dst, deg, N_EDGES);
  scan_off<<<1, 256, 0, stream>>>(deg, off, N_NODES);
  hipMemcpyAsync(cursor, off, (size_t)N_NODES * 4, hipMemcpyDeviceToDevice, stream);
  fill_csr<<<1875, 256, 0, stream>>>(src, dst, cursor, esrc, N_EDGES);

  // --- weight prep ---
  transpose_k<<<64, 256, 0, stream>>>(enc_Wpool, wt_encpool, 128, 7, 128, 0);
  transpose_k<<<128, 256, 0, stream>>>(enc_Wself, wt_enc, 128, 8, 256, 0);
  transpose_k<<<128, 256, 0, stream>>>(enc_Wneigh, wt_enc, 128, 8, 256, 128);
  transpose_k<<<256, 256, 0, stream>>>(dec_Wpool, wt_decpool, 256, 8, 256, 0);
  transpose_k<<<128, 256, 0, stream>>>(dec_Wself, wt_dec, 256, 7, 512, 0);
  transpose_k<<<128, 256, 0, stream>>>(dec_Wneigh, wt_dec, 256, 7, 512, 256);
  // wt_U = W1 rows [0..255 | 256..260 | zero-pad to 288]; wt_V = rows [267..522 | 523..527 | pad]
  hipMemsetAsync(wt_U, 0, 256 * 288 * 2, stream);
  hipMemsetAsync(wt_V, 0, 256 * 288 * 2, stream);
  transpose_k<<<256, 256, 0, stream>>>(ep_W1, wt_U, 256, 8, 288, 0);
  transpose_k<<<5, 256, 0, stream>>>(ep_W1 + 256 * 256, wt_U, 5, 8, 288, 256);
  transpose_k<<<256, 256, 0, stream>>>(ep_W1 + 267 * 256, wt_V, 256, 8, 288, 0);
  transpose_k<<<5, 256, 0, stream>>>(ep_W1 + 523 * 256, wt_V, 5, 8, 288, 256);

  // --- encoder ---
  gemm_mfma<<<dim3(235, 1), 256, 0, stream>>>(c_h, nullptr, 128, 0, wt_encpool,
                                              enc_bpool, 1, m_buf, nullptr, flag, N_NODES, 128);
  agg128<<<7500, 256, 0, stream>>>(m_buf, esrc, off, aggb);
  gemm_mfma<<<dim3(235, 2), 256, 0, stream>>>(c_h, aggb, 128, 128, wt_enc,
                                              enc_bself, 1, h1b, nullptr, flag, N_NODES, 256);
  // --- node head (also emits padded softmax rows) ---
  node_head<<<118, 256, 0, stream>>>(h1b, np_W, np_b, np_g, np_beta, outN, outNf, flag, smb32);
  // --- edge head: U/V precompute (alias m_buf/aggb), then pointwise edge kernel ---
  gemm_mfma<<<dim3(235, 2), 256, 0, stream>>>(h1b, smb32, 256, 32, wt_U,
                                              ep_b1, 0, m_buf, nullptr, flag, N_NODES, 256);
  gemm_mfma<<<dim3(235, 2), 256, 0, stream>>>(h1b, smb32, 256, 32, wt_V,
                                              nullptr, 0, aggb, nullptr, flag, N_NODES, 256);
  edge_pt<<<1920, 256, 0, stream>>>(m_buf, aggb, c_ef, src, dst, ep_W1,
                                    ep_g, ep_beta, ep_W2, ep_b2, outE, outEf, flag);
  // --- decoder (m_buf/aggb reusable again) ---
  gemm_mfma<<<dim3(235, 2), 256, 0, stream>>>(h1b, nullptr, 256, 0, wt_decpool,
                                              dec_bpool, 1, m_buf, nullptr, flag, N_NODES, 256);
  agg256<<<7500, 256, 0, stream>>>(m_buf, esrc, off, aggb);
  gemm_mfma<<<dim3(235, 1), 256, 0, stream>>>(h1b, aggb, 256, 256, wt_dec,
                                              dec_bself, 1, outH, outHf, flag, N_NODES, 128);
}